// Round 1
// baseline (3803.532 us; speedup 1.0000x reference)
//
#include <hip/hip_runtime.h>
#include <math.h>

constexpr int   NGc   = 128;
constexpr float DTc   = 1e-4f;
constexpr float DXc   = 1.0f / 128.0f;
constexpr float INV_DX = 128.0f;
constexpr float P_VOLc = (DXc * 0.5f) * (DXc * 0.5f);
constexpr float P_MASSc = P_VOLc * 1.0f;
constexpr float GRAV  = 9.8f;
// -DT * P_VOL * 4 * inv_dx^2  (== -DT exactly for these constants, computed generically)
constexpr float STRESS_COEF = -DTc * P_VOLc * 4.0f * INV_DX * INV_DX;

// ---------------------------------------------------------------------------
// P2G: per-particle NN stress (fwd+bwd), affine, scatter-add into 7-plane grid
// ---------------------------------------------------------------------------
__global__ __launch_bounds__(256) void p2g_kernel(
    const float2* __restrict__ x, const float2* __restrict__ v,
    const float4* __restrict__ C, const float4* __restrict__ F,
    const float* __restrict__ W1, const float* __restrict__ b1,
    const float* __restrict__ W2, const float* __restrict__ b2,
    const float* __restrict__ W3, const float* __restrict__ b3,
    const float* __restrict__ W4,
    float* __restrict__ grid, float4* __restrict__ Fnew_out, int n)
{
    int i = blockIdx.x * 256 + threadIdx.x;
    if (i >= n) return;

    float2 xi = x[i];
    float2 vi = v[i];
    float4 Ci = C[i];
    float4 Fi = F[i];

    // F_new = F + DT * (C @ F)
    float Fn00 = Fi.x + DTc * (Ci.x * Fi.x + Ci.y * Fi.z);
    float Fn01 = Fi.y + DTc * (Ci.x * Fi.y + Ci.y * Fi.w);
    float Fn10 = Fi.z + DTc * (Ci.z * Fi.x + Ci.w * Fi.z);
    float Fn11 = Fi.w + DTc * (Ci.z * Fi.y + Ci.w * Fi.w);

    // Cm = Fn^T Fn (symmetric; Cm01 == Cm10 bitwise in the reference too)
    float Cm00 = Fn00 * Fn00 + Fn10 * Fn10;
    float Cm01 = Fn00 * Fn01 + Fn10 * Fn11;
    float Cm11 = Fn01 * Fn01 + Fn11 * Fn11;

    float tr  = Cm00 + Cm11;
    float det = Cm00 * Cm11 - Cm01 * Cm01;
    float g   = tr * tr - 4.0f * det;
    float gate = (g > 1e-8f) ? 1.0f : 0.0f;
    float gc  = fmaxf(g, 1e-8f);
    float delta = sqrtf(gc);
    float feat0 = 0.5f * (tr + delta);
    float feat1 = 0.5f * (tr - delta);

    // ---- MLP forward (weights are thread-uniform -> scalar loads) ----
    float h1[16], h2[16], h3[16];
#pragma unroll
    for (int j = 0; j < 16; j++) {
        h1[j] = fmaxf(W1[2 * j] * feat0 + W1[2 * j + 1] * feat1 + b1[j], 0.0f);
    }
#pragma unroll
    for (int j = 0; j < 16; j++) {
        float a = b2[j];
#pragma unroll
        for (int k = 0; k < 16; k++) a += W2[j * 16 + k] * h1[k];
        h2[j] = fmaxf(a, 0.0f);
    }
#pragma unroll
    for (int j = 0; j < 16; j++) {
        float a = b3[j];
#pragma unroll
        for (int k = 0; k < 16; k++) a += W3[j * 16 + k] * h2[k];
        h3[j] = fmaxf(a, 0.0f);
    }

    // ---- backward: dpsi/dfeat ----
    float dh3[16];
#pragma unroll
    for (int j = 0; j < 16; j++) dh3[j] = (h3[j] > 0.0f) ? W4[j] : 0.0f;

    float dh2[16];
#pragma unroll
    for (int k = 0; k < 16; k++) {
        float a = 0.0f;
#pragma unroll
        for (int j = 0; j < 16; j++) a += W3[j * 16 + k] * dh3[j];
        dh2[k] = (h2[k] > 0.0f) ? a : 0.0f;
    }

    float dfeat0 = 0.0f, dfeat1 = 0.0f;
#pragma unroll
    for (int k = 0; k < 16; k++) {
        float a = 0.0f;
#pragma unroll
        for (int j = 0; j < 16; j++) a += W2[j * 16 + k] * dh2[j];
        float dh1k = (h1[k] > 0.0f) ? a : 0.0f;
        dfeat0 += W1[2 * k] * dh1k;
        dfeat1 += W1[2 * k + 1] * dh1k;
    }

    // feat -> (tr, det) -> Cm
    float half_sum  = 0.5f * (dfeat0 + dfeat1);
    float half_diff = 0.5f * (dfeat0 - dfeat1);   // coefficient on delta
    float inv_delta = 1.0f / delta;
    float dtr  = half_sum + half_diff * tr * inv_delta * gate;   // d/d tr
    float ddet = half_diff * (-2.0f) * inv_delta * gate;         // d/d det

    // G = dpsi/dCm ; S = G + G^T (symmetric)
    float S00 = 2.0f * (dtr + ddet * Cm11);
    float S11 = 2.0f * (dtr + ddet * Cm00);
    float S01 = -2.0f * ddet * Cm01;

    // dpsi/dF = Fn @ S
    float dF00 = Fn00 * S00 + Fn01 * S01;
    float dF01 = Fn00 * S01 + Fn01 * S11;
    float dF10 = Fn10 * S00 + Fn11 * S01;
    float dF11 = Fn10 * S01 + Fn11 * S11;

    // affine = stress + p_mass * C
    float a00 = STRESS_COEF * dF00 + P_MASSc * Ci.x;
    float a01 = STRESS_COEF * dF01 + P_MASSc * Ci.y;
    float a10 = STRESS_COEF * dF10 + P_MASSc * Ci.z;
    float a11 = STRESS_COEF * dF11 + P_MASSc * Ci.w;

    float vax = P_MASSc * vi.x - (a00 * xi.x + a01 * xi.y);
    float vay = P_MASSc * vi.y - (a10 * xi.x + a11 * xi.y);

    // quadratic B-spline weights
    float px = xi.x * INV_DX, py = xi.y * INV_DX;
    int   bx = (int)floorf(px - 0.5f);
    int   by = (int)floorf(py - 0.5f);
    float fx = px - (float)bx;
    float fy = py - (float)by;
    float wx0 = 0.5f * (1.5f - fx) * (1.5f - fx);
    float wx1 = 0.75f - (fx - 1.0f) * (fx - 1.0f);
    float wx2 = 0.5f * (fx - 0.5f) * (fx - 0.5f);
    float wy0 = 0.5f * (1.5f - fy) * (1.5f - fy);
    float wy1 = 0.75f - (fy - 1.0f) * (fy - 1.0f);
    float wy2 = 0.5f * (fy - 0.5f) * (fy - 0.5f);
    float wxs[3] = {wx0, wx1, wx2};
    float wys[3] = {wy0, wy1, wy2};

    Fnew_out[i] = make_float4(Fn00, Fn01, Fn10, Fn11);

#pragma unroll
    for (int ii = 0; ii < 3; ii++) {
#pragma unroll
        for (int jj = 0; jj < 3; jj++) {
            float wt = wxs[ii] * wys[jj];
            float* cell = grid + ((size_t)((bx + ii) * NGc + (by + jj))) * 7;
            atomicAdd(cell + 0, wt * vax);
            atomicAdd(cell + 1, wt * vay);
            atomicAdd(cell + 2, wt * a00);
            atomicAdd(cell + 3, wt * a01);
            atomicAdd(cell + 4, wt * a10);
            atomicAdd(cell + 5, wt * a11);
            atomicAdd(cell + 6, wt * P_MASSc);
        }
    }
}

// ---------------------------------------------------------------------------
// Grid update: momentum -> velocity, gravity, boundaries. Emits float2 per node.
// ---------------------------------------------------------------------------
__global__ __launch_bounds__(256) void grid_kernel(const float* __restrict__ grid,
                                                   float2* __restrict__ gv)
{
    int idx = blockIdx.x * 256 + threadIdx.x;
    if (idx >= NGc * NGc) return;
    int i = idx >> 7;        // / 128
    int j = idx & 127;       // % 128

    const float* c = grid + (size_t)idx * 7;
    float g0 = c[0], g1 = c[1], A00 = c[2], A01 = c[3], A10 = c[4], A11 = c[5], m = c[6];

    float gxx = (float)i * DXc;
    float gxy = (float)j * DXc;
    float vx = g0 + A00 * gxx + A01 * gxy;
    float vy = g1 + A10 * gxx + A11 * gxy;
    if (m > 0.0f) {
        float inv_m = 1.0f / m;
        vx *= inv_m;
        vy *= inv_m;
    }
    vy -= DTc * GRAV;
    if (i < 3)        vx = fmaxf(vx, 0.0f);
    if (i >= NGc - 3) vx = fminf(vx, 0.0f);
    if (j < 3)        vy = fmaxf(vy, 0.0f);
    if (j >= NGc - 3) vy = fminf(vy, 0.0f);

    gv[idx] = make_float2(vx, vy);
}

// ---------------------------------------------------------------------------
// G2P: gather velocity + on-the-fly grid_C = v ⊗ gx, write all outputs
// ---------------------------------------------------------------------------
__global__ __launch_bounds__(256) void g2p_kernel(
    const float2* __restrict__ x, const float2* __restrict__ v,
    const int* __restrict__ material, const float* __restrict__ Jp,
    const float2* __restrict__ gv,
    float2* __restrict__ out_x, float2* __restrict__ out_v,
    float4* __restrict__ out_C, float* __restrict__ out_mat,
    float* __restrict__ out_Jp, int n)
{
    int i = blockIdx.x * 256 + threadIdx.x;
    if (i >= n) return;

    float2 xi = x[i];
    float2 vi = v[i];

    float px = xi.x * INV_DX, py = xi.y * INV_DX;
    int   bx = (int)floorf(px - 0.5f);
    int   by = (int)floorf(py - 0.5f);
    float fx = px - (float)bx;
    float fy = py - (float)by;
    float wxs[3] = {0.5f * (1.5f - fx) * (1.5f - fx),
                    0.75f - (fx - 1.0f) * (fx - 1.0f),
                    0.5f * (fx - 0.5f) * (fx - 0.5f)};
    float wys[3] = {0.5f * (1.5f - fy) * (1.5f - fy),
                    0.75f - (fy - 1.0f) * (fy - 1.0f),
                    0.5f * (fy - 0.5f) * (fy - 0.5f)};

    float accvx = 0.0f, accvy = 0.0f;
    float accC00 = 0.0f, accC01 = 0.0f, accC10 = 0.0f, accC11 = 0.0f;

#pragma unroll
    for (int ii = 0; ii < 3; ii++) {
        float gxx = (float)(bx + ii) * DXc;
#pragma unroll
        for (int jj = 0; jj < 3; jj++) {
            float wt = wxs[ii] * wys[jj];
            float2 gvn = gv[(bx + ii) * NGc + (by + jj)];
            float gxy = (float)(by + jj) * DXc;
            accvx  += wt * gvn.x;
            accvy  += wt * gvn.y;
            accC00 += wt * gvn.x * gxx;
            accC01 += wt * gvn.x * gxy;
            accC10 += wt * gvn.y * gxx;
            accC11 += wt * gvn.y * gxy;
        }
    }

    const float k4 = 4.0f * INV_DX * INV_DX;
    float nC00 = k4 * (accC00 - accvx * xi.x);
    float nC01 = k4 * (accC01 - accvx * xi.y);
    float nC10 = k4 * (accC10 - accvy * xi.x);
    float nC11 = k4 * (accC11 - accvy * xi.y);

    out_x[i]   = make_float2(xi.x + DTc * vi.x, xi.y + DTc * vi.y);
    out_v[i]   = make_float2(accvx, accvy);
    out_C[i]   = make_float4(nC00, nC01, nC10, nC11);
    out_mat[i] = (float)material[i];
    out_Jp[i]  = Jp[i];
}

// ---------------------------------------------------------------------------
extern "C" void kernel_launch(void* const* d_in, const int* in_sizes, int n_in,
                              void* d_out, int out_size, void* d_ws, size_t ws_size,
                              hipStream_t stream)
{
    const float2* x  = (const float2*)d_in[0];
    const float2* v  = (const float2*)d_in[1];
    const float4* C  = (const float4*)d_in[2];
    const float4* F  = (const float4*)d_in[3];
    const int* material = (const int*)d_in[4];
    const float* Jp  = (const float*)d_in[5];
    const float* W1  = (const float*)d_in[8];
    const float* b1  = (const float*)d_in[9];
    const float* W2  = (const float*)d_in[10];
    const float* b2  = (const float*)d_in[11];
    const float* W3  = (const float*)d_in[12];
    const float* b3  = (const float*)d_in[13];
    const float* W4  = (const float*)d_in[14];

    const int n = in_sizes[0] / 2;

    float*  grid = (float*)d_ws;                                        // 7*128*128 floats
    float2* gv   = (float2*)((char*)d_ws + 7 * NGc * NGc * sizeof(float)); // 2*128*128 floats

    float* out = (float*)d_out;
    float2* out_x   = (float2*)out;                    // 2N
    float2* out_v   = (float2*)(out + 2 * (size_t)n);  // 2N
    float4* out_C   = (float4*)(out + 4 * (size_t)n);  // 4N
    float4* out_F   = (float4*)(out + 8 * (size_t)n);  // 4N
    float*  out_mat = out + 12 * (size_t)n;            // N
    float*  out_Jp  = out + 13 * (size_t)n;            // N

    hipMemsetAsync(d_ws, 0, 7 * NGc * NGc * sizeof(float), stream);

    int blocks = (n + 255) / 256;
    p2g_kernel<<<blocks, 256, 0, stream>>>(x, v, C, F, W1, b1, W2, b2, W3, b3, W4,
                                           grid, out_F, n);
    grid_kernel<<<(NGc * NGc + 255) / 256, 256, 0, stream>>>(grid, gv);
    g2p_kernel<<<blocks, 256, 0, stream>>>(x, v, material, Jp, gv,
                                           out_x, out_v, out_C, out_mat, out_Jp, n);
}

// Round 2
// 1580.002 us; speedup vs baseline: 2.4073x; 2.4073x over previous
//
#include <hip/hip_runtime.h>
#include <math.h>

constexpr int   NGc    = 128;
constexpr int   NCELL  = NGc * NGc;
constexpr int   NREP   = 8;                 // one grid replica per XCD
constexpr float DTc    = 1e-4f;
constexpr float DXc    = 1.0f / 128.0f;
constexpr float INV_DX = 128.0f;
constexpr float P_VOLc = (DXc * 0.5f) * (DXc * 0.5f);
constexpr float P_MASSc = P_VOLc * 1.0f;
constexpr float GRAV   = 9.8f;
constexpr float STRESS_COEF = -DTc * P_VOLc * 4.0f * INV_DX * INV_DX;

// ---------------------------------------------------------------------------
// XCD id of the executing wave (HW_REG_XCC_ID = hwreg 20, 4-bit field).
// imm = (size-1)<<11 | offset<<6 | id = 3<<11 | 0 | 20 = 6164
// ---------------------------------------------------------------------------
__device__ __forceinline__ int xcc_id() {
    return __builtin_amdgcn_s_getreg(6164) & 7;
}

// L2-local (XCD-scope) fp32 atomic add: global_atomic_add_f32 with no sc0/sc1
// bits -> RMW performed in this XCD's L2, no fabric write-through.
__device__ __forceinline__ void atomic_add_l2(float* p, float v) {
    asm volatile("global_atomic_add_f32 %0, %1, off" :: "v"(p), "v"(v) : "memory");
}

// ---------------------------------------------------------------------------
// P2G: NN stress (fwd + analytic bwd), momentum-form scatter into the XCD's
// replica: 9 nodes x {mom_x, mom_y, mass} = 27 L2-local atomics / particle.
// ---------------------------------------------------------------------------
__global__ __launch_bounds__(256) void p2g_kernel(
    const float2* __restrict__ x, const float2* __restrict__ v,
    const float4* __restrict__ C, const float4* __restrict__ F,
    const float* __restrict__ W1, const float* __restrict__ b1,
    const float* __restrict__ W2, const float* __restrict__ b2,
    const float* __restrict__ W3, const float* __restrict__ b3,
    const float* __restrict__ W4,
    float* __restrict__ grid, float4* __restrict__ Fnew_out, int n)
{
    int i = blockIdx.x * 256 + threadIdx.x;
    if (i >= n) return;

    float2 xi = x[i];
    float2 vi = v[i];
    float4 Ci = C[i];
    float4 Fi = F[i];

    // F_new = F + DT * (C @ F)
    float Fn00 = Fi.x + DTc * (Ci.x * Fi.x + Ci.y * Fi.z);
    float Fn01 = Fi.y + DTc * (Ci.x * Fi.y + Ci.y * Fi.w);
    float Fn10 = Fi.z + DTc * (Ci.z * Fi.x + Ci.w * Fi.z);
    float Fn11 = Fi.w + DTc * (Ci.z * Fi.y + Ci.w * Fi.w);

    // Cm = Fn^T Fn
    float Cm00 = Fn00 * Fn00 + Fn10 * Fn10;
    float Cm01 = Fn00 * Fn01 + Fn10 * Fn11;
    float Cm11 = Fn01 * Fn01 + Fn11 * Fn11;

    float tr  = Cm00 + Cm11;
    float det = Cm00 * Cm11 - Cm01 * Cm01;
    float g   = tr * tr - 4.0f * det;
    float gate = (g > 1e-8f) ? 1.0f : 0.0f;
    float delta = sqrtf(fmaxf(g, 1e-8f));
    float feat0 = 0.5f * (tr + delta);
    float feat1 = 0.5f * (tr - delta);

    // ---- MLP forward (thread-uniform weights -> scalar loads) ----
    float h1[16], h2[16], h3[16];
#pragma unroll
    for (int j = 0; j < 16; j++)
        h1[j] = fmaxf(W1[2 * j] * feat0 + W1[2 * j + 1] * feat1 + b1[j], 0.0f);
#pragma unroll
    for (int j = 0; j < 16; j++) {
        float a = b2[j];
#pragma unroll
        for (int k = 0; k < 16; k++) a += W2[j * 16 + k] * h1[k];
        h2[j] = fmaxf(a, 0.0f);
    }
#pragma unroll
    for (int j = 0; j < 16; j++) {
        float a = b3[j];
#pragma unroll
        for (int k = 0; k < 16; k++) a += W3[j * 16 + k] * h2[k];
        h3[j] = fmaxf(a, 0.0f);
    }

    // ---- backward ----
    float dh3[16];
#pragma unroll
    for (int j = 0; j < 16; j++) dh3[j] = (h3[j] > 0.0f) ? W4[j] : 0.0f;

    float dh2[16];
#pragma unroll
    for (int k = 0; k < 16; k++) {
        float a = 0.0f;
#pragma unroll
        for (int j = 0; j < 16; j++) a += W3[j * 16 + k] * dh3[j];
        dh2[k] = (h2[k] > 0.0f) ? a : 0.0f;
    }

    float dfeat0 = 0.0f, dfeat1 = 0.0f;
#pragma unroll
    for (int k = 0; k < 16; k++) {
        float a = 0.0f;
#pragma unroll
        for (int j = 0; j < 16; j++) a += W2[j * 16 + k] * dh2[j];
        float dh1k = (h1[k] > 0.0f) ? a : 0.0f;
        dfeat0 += W1[2 * k] * dh1k;
        dfeat1 += W1[2 * k + 1] * dh1k;
    }

    float half_sum  = 0.5f * (dfeat0 + dfeat1);
    float half_diff = 0.5f * (dfeat0 - dfeat1);
    float inv_delta = 1.0f / delta;
    float dtr  = half_sum + half_diff * tr * inv_delta * gate;
    float ddet = half_diff * (-2.0f) * inv_delta * gate;

    float S00 = 2.0f * (dtr + ddet * Cm11);
    float S11 = 2.0f * (dtr + ddet * Cm00);
    float S01 = -2.0f * ddet * Cm01;

    float dF00 = Fn00 * S00 + Fn01 * S01;
    float dF01 = Fn00 * S01 + Fn01 * S11;
    float dF10 = Fn10 * S00 + Fn11 * S01;
    float dF11 = Fn10 * S01 + Fn11 * S11;

    // affine = stress + p_mass * C
    float a00 = STRESS_COEF * dF00 + P_MASSc * Ci.x;
    float a01 = STRESS_COEF * dF01 + P_MASSc * Ci.y;
    float a10 = STRESS_COEF * dF10 + P_MASSc * Ci.z;
    float a11 = STRESS_COEF * dF11 + P_MASSc * Ci.w;

    float pvx = P_MASSc * vi.x;
    float pvy = P_MASSc * vi.y;

    // B-spline weights
    float px = xi.x * INV_DX, py = xi.y * INV_DX;
    int   bx = (int)floorf(px - 0.5f);
    int   by = (int)floorf(py - 0.5f);
    float fx = px - (float)bx;
    float fy = py - (float)by;
    float wxs[3] = {0.5f * (1.5f - fx) * (1.5f - fx),
                    0.75f - (fx - 1.0f) * (fx - 1.0f),
                    0.5f * (fx - 0.5f) * (fx - 0.5f)};
    float wys[3] = {0.5f * (1.5f - fy) * (1.5f - fy),
                    0.75f - (fy - 1.0f) * (fy - 1.0f),
                    0.5f * (fy - 0.5f) * (fy - 0.5f)};

    Fnew_out[i] = make_float4(Fn00, Fn01, Fn10, Fn11);

    // this XCD's replica (plane-major: 3 planes of NCELL)
    float* rep = grid + (size_t)xcc_id() * (3 * NCELL);

#pragma unroll
    for (int ii = 0; ii < 3; ii++) {
        float dxp = ((float)ii - fx) * DXc;   // gx_node.x - x_p.x
#pragma unroll
        for (int jj = 0; jj < 3; jj++) {
            float dyp = ((float)jj - fy) * DXc;
            float wt = wxs[ii] * wys[jj];
            int cell = (bx + ii) * NGc + (by + jj);
            float momx = wt * (pvx + a00 * dxp + a01 * dyp);
            float momy = wt * (pvy + a10 * dxp + a11 * dyp);
            atomic_add_l2(rep + cell,             momx);
            atomic_add_l2(rep + NCELL + cell,     momy);
            atomic_add_l2(rep + 2 * NCELL + cell, wt * P_MASSc);
        }
    }
}

// ---------------------------------------------------------------------------
// Reduce 8 replicas -> grid velocity (gravity + boundaries fused)
// ---------------------------------------------------------------------------
__global__ __launch_bounds__(256) void grid_reduce_kernel(
    const float* __restrict__ grid, float2* __restrict__ gv)
{
    int idx = blockIdx.x * 256 + threadIdx.x;
    if (idx >= NCELL) return;
    int i = idx >> 7;
    int j = idx & 127;

    float momx = 0.0f, momy = 0.0f, m = 0.0f;
#pragma unroll
    for (int r = 0; r < NREP; r++) {
        const float* rep = grid + (size_t)r * (3 * NCELL);
        momx += rep[idx];
        momy += rep[NCELL + idx];
        m    += rep[2 * NCELL + idx];
    }

    float vx = momx, vy = momy;
    if (m > 0.0f) {
        float inv_m = 1.0f / m;
        vx *= inv_m;
        vy *= inv_m;
    }
    vy -= DTc * GRAV;
    if (i < 3)        vx = fmaxf(vx, 0.0f);
    if (i >= NGc - 3) vx = fminf(vx, 0.0f);
    if (j < 3)        vy = fmaxf(vy, 0.0f);
    if (j >= NGc - 3) vy = fminf(vy, 0.0f);

    gv[idx] = make_float2(vx, vy);
}

// ---------------------------------------------------------------------------
// G2P: gather velocity + on-the-fly grid_C = v ⊗ gx, write outputs
// ---------------------------------------------------------------------------
__global__ __launch_bounds__(256) void g2p_kernel(
    const float2* __restrict__ x, const float2* __restrict__ v,
    const int* __restrict__ material, const float* __restrict__ Jp,
    const float2* __restrict__ gv,
    float2* __restrict__ out_x, float2* __restrict__ out_v,
    float4* __restrict__ out_C, float* __restrict__ out_mat,
    float* __restrict__ out_Jp, int n)
{
    int i = blockIdx.x * 256 + threadIdx.x;
    if (i >= n) return;

    float2 xi = x[i];
    float2 vi = v[i];

    float px = xi.x * INV_DX, py = xi.y * INV_DX;
    int   bx = (int)floorf(px - 0.5f);
    int   by = (int)floorf(py - 0.5f);
    float fx = px - (float)bx;
    float fy = py - (float)by;
    float wxs[3] = {0.5f * (1.5f - fx) * (1.5f - fx),
                    0.75f - (fx - 1.0f) * (fx - 1.0f),
                    0.5f * (fx - 0.5f) * (fx - 0.5f)};
    float wys[3] = {0.5f * (1.5f - fy) * (1.5f - fy),
                    0.75f - (fy - 1.0f) * (fy - 1.0f),
                    0.5f * (fy - 0.5f) * (fy - 0.5f)};

    float accvx = 0.0f, accvy = 0.0f;
    float accC00 = 0.0f, accC01 = 0.0f, accC10 = 0.0f, accC11 = 0.0f;

#pragma unroll
    for (int ii = 0; ii < 3; ii++) {
        float gxx = (float)(bx + ii) * DXc;
#pragma unroll
        for (int jj = 0; jj < 3; jj++) {
            float wt = wxs[ii] * wys[jj];
            float2 gvn = gv[(bx + ii) * NGc + (by + jj)];
            float gxy = (float)(by + jj) * DXc;
            accvx  += wt * gvn.x;
            accvy  += wt * gvn.y;
            accC00 += wt * gvn.x * gxx;
            accC01 += wt * gvn.x * gxy;
            accC10 += wt * gvn.y * gxx;
            accC11 += wt * gvn.y * gxy;
        }
    }

    const float k4 = 4.0f * INV_DX * INV_DX;
    float nC00 = k4 * (accC00 - accvx * xi.x);
    float nC01 = k4 * (accC01 - accvx * xi.y);
    float nC10 = k4 * (accC10 - accvy * xi.x);
    float nC11 = k4 * (accC11 - accvy * xi.y);

    out_x[i]   = make_float2(xi.x + DTc * vi.x, xi.y + DTc * vi.y);
    out_v[i]   = make_float2(accvx, accvy);
    out_C[i]   = make_float4(nC00, nC01, nC10, nC11);
    out_mat[i] = (float)material[i];
    out_Jp[i]  = Jp[i];
}

// ---------------------------------------------------------------------------
extern "C" void kernel_launch(void* const* d_in, const int* in_sizes, int n_in,
                              void* d_out, int out_size, void* d_ws, size_t ws_size,
                              hipStream_t stream)
{
    const float2* x  = (const float2*)d_in[0];
    const float2* v  = (const float2*)d_in[1];
    const float4* C  = (const float4*)d_in[2];
    const float4* F  = (const float4*)d_in[3];
    const int* material = (const int*)d_in[4];
    const float* Jp  = (const float*)d_in[5];
    const float* W1  = (const float*)d_in[8];
    const float* b1  = (const float*)d_in[9];
    const float* W2  = (const float*)d_in[10];
    const float* b2  = (const float*)d_in[11];
    const float* W3  = (const float*)d_in[12];
    const float* b3  = (const float*)d_in[13];
    const float* W4  = (const float*)d_in[14];

    const int n = in_sizes[0] / 2;

    float*  grid = (float*)d_ws;                       // NREP * 3 * NCELL floats
    float2* gv   = (float2*)((char*)d_ws + (size_t)NREP * 3 * NCELL * sizeof(float));

    float* out = (float*)d_out;
    float2* out_x   = (float2*)out;
    float2* out_v   = (float2*)(out + 2 * (size_t)n);
    float4* out_C   = (float4*)(out + 4 * (size_t)n);
    float4* out_F   = (float4*)(out + 8 * (size_t)n);
    float*  out_mat = out + 12 * (size_t)n;
    float*  out_Jp  = out + 13 * (size_t)n;

    hipMemsetAsync(d_ws, 0, (size_t)NREP * 3 * NCELL * sizeof(float), stream);

    int blocks = (n + 255) / 256;
    p2g_kernel<<<blocks, 256, 0, stream>>>(x, v, C, F, W1, b1, W2, b2, W3, b3, W4,
                                           grid, (float4*)out_F, n);
    grid_reduce_kernel<<<(NCELL + 255) / 256, 256, 0, stream>>>(grid, gv);
    g2p_kernel<<<blocks, 256, 0, stream>>>(x, v, material, Jp, gv,
                                           out_x, out_v, out_C, out_mat, out_Jp, n);
}

// Round 3
// 509.845 us; speedup vs baseline: 7.4602x; 3.0990x over previous
//
#include <hip/hip_runtime.h>
#include <math.h>

constexpr int   NGc    = 128;
constexpr int   NCELL  = NGc * NGc;
constexpr int   NTILE  = 32;                // 32x32 tiles of 4x4 cells
constexpr int   NBIN   = NTILE * NTILE;     // 1024
constexpr float DTc    = 1e-4f;
constexpr float DXc    = 1.0f / 128.0f;
constexpr float INV_DX = 128.0f;
constexpr float P_VOLc = (DXc * 0.5f) * (DXc * 0.5f);
constexpr float P_MASSc = P_VOLc * 1.0f;
constexpr float GRAV   = 9.8f;
constexpr float STRESS_COEF = -DTc * P_VOLc * 4.0f * INV_DX * INV_DX;

__device__ __forceinline__ int tile_of(float2 xi, int& bx, int& by) {
    bx = (int)floorf(xi.x * INV_DX - 0.5f);
    by = (int)floorf(xi.y * INV_DX - 0.5f);
    return (bx >> 2) * NTILE + (by >> 2);
}

// ---------------------------------------------------------------------------
// S1: per-block LDS histogram + local rank, merge to global (atomic returns
// this block's base within the bin), emit packed key = tile<<20 | pos_in_bin.
// ---------------------------------------------------------------------------
constexpr int S1_PPT = 8;                       // particles per thread
constexpr int S1_BLK = 1024;

__global__ __launch_bounds__(1024) void bin_kernel(
    const float2* __restrict__ x, unsigned* __restrict__ key,
    unsigned* __restrict__ gcnt, int n)
{
    __shared__ unsigned hist[NBIN];
    hist[threadIdx.x] = 0;                      // blockDim == NBIN == 1024
    __syncthreads();

    int base_i = blockIdx.x * (S1_BLK * S1_PPT);
    unsigned t_arr[S1_PPT], r_arr[S1_PPT];
#pragma unroll
    for (int k = 0; k < S1_PPT; k++) {
        int i = base_i + k * S1_BLK + threadIdx.x;
        unsigned t = 0, r = 0;
        if (i < n) {
            int bx, by;
            t = (unsigned)tile_of(x[i], bx, by);
            r = atomicAdd(&hist[t], 1u);
        }
        t_arr[k] = t; r_arr[k] = r;
    }
    __syncthreads();

    unsigned c = hist[threadIdx.x];
    __syncthreads();
    hist[threadIdx.x] = c ? atomicAdd(&gcnt[threadIdx.x], c) : 0u;
    __syncthreads();

#pragma unroll
    for (int k = 0; k < S1_PPT; k++) {
        int i = base_i + k * S1_BLK + threadIdx.x;
        if (i < n)
            key[i] = (t_arr[k] << 20) | (hist[t_arr[k]] + r_arr[k]);
    }
}

// ---------------------------------------------------------------------------
// S2: exclusive scan over 1024 bin counts (single block)
// ---------------------------------------------------------------------------
__global__ __launch_bounds__(1024) void scan_kernel(
    const unsigned* __restrict__ gcnt, unsigned* __restrict__ binoff)
{
    __shared__ unsigned s[NBIN];
    unsigned v = gcnt[threadIdx.x];
    s[threadIdx.x] = v;
    __syncthreads();
    for (int d = 1; d < NBIN; d <<= 1) {
        unsigned add = (threadIdx.x >= (unsigned)d) ? s[threadIdx.x - d] : 0u;
        __syncthreads();
        s[threadIdx.x] += add;
        __syncthreads();
    }
    binoff[threadIdx.x] = s[threadIdx.x] - v;
}

// ---------------------------------------------------------------------------
// S3: scatter particle index into sorted order
// ---------------------------------------------------------------------------
__global__ __launch_bounds__(256) void scatter_kernel(
    const unsigned* __restrict__ key, const unsigned* __restrict__ binoff,
    unsigned* __restrict__ sortedIdx, int n)
{
    int i = blockIdx.x * 256 + threadIdx.x;
    if (i >= n) return;
    unsigned k = key[i];
    unsigned t = k >> 20, pos = k & 0xFFFFFu;
    sortedIdx[binoff[t] + pos] = (unsigned)i;
}

// ---------------------------------------------------------------------------
// P2G: one block per tile. NN stress per particle, momentum-form scatter into
// 6x6x3 LDS window via LDS atomics; one global-atomic merge per LDS cell.
// ---------------------------------------------------------------------------
__global__ __launch_bounds__(256) void p2g_kernel(
    const float2* __restrict__ x, const float2* __restrict__ v,
    const float4* __restrict__ C, const float4* __restrict__ F,
    const float* __restrict__ W1, const float* __restrict__ b1,
    const float* __restrict__ W2, const float* __restrict__ b2,
    const float* __restrict__ W3, const float* __restrict__ b3,
    const float* __restrict__ W4,
    const unsigned* __restrict__ gcnt, const unsigned* __restrict__ binoff,
    const unsigned* __restrict__ sortedIdx,
    float* __restrict__ grid, float4* __restrict__ Fnew_out)
{
    int t = blockIdx.x;
    int cnt = (int)gcnt[t];
    if (cnt == 0) return;
    int base = (int)binoff[t];
    int ox = (t >> 5) << 2;     // tile origin cell
    int oy = (t & 31) << 2;

    __shared__ float lacc[3 * 36];              // 3 planes x 6x6 cells
    if (threadIdx.x < 108) lacc[threadIdx.x] = 0.0f;
    __syncthreads();

    for (int k = threadIdx.x; k < cnt; k += 256) {
        int i = (int)sortedIdx[base + k];

        float2 xi = x[i];
        float2 vi = v[i];
        float4 Ci = C[i];
        float4 Fi = F[i];

        // F_new = F + DT * (C @ F)
        float Fn00 = Fi.x + DTc * (Ci.x * Fi.x + Ci.y * Fi.z);
        float Fn01 = Fi.y + DTc * (Ci.x * Fi.y + Ci.y * Fi.w);
        float Fn10 = Fi.z + DTc * (Ci.z * Fi.x + Ci.w * Fi.z);
        float Fn11 = Fi.w + DTc * (Ci.z * Fi.y + Ci.w * Fi.w);

        float Cm00 = Fn00 * Fn00 + Fn10 * Fn10;
        float Cm01 = Fn00 * Fn01 + Fn10 * Fn11;
        float Cm11 = Fn01 * Fn01 + Fn11 * Fn11;

        float tr  = Cm00 + Cm11;
        float det = Cm00 * Cm11 - Cm01 * Cm01;
        float g   = tr * tr - 4.0f * det;
        float gate = (g > 1e-8f) ? 1.0f : 0.0f;
        float delta = sqrtf(fmaxf(g, 1e-8f));
        float feat0 = 0.5f * (tr + delta);
        float feat1 = 0.5f * (tr - delta);

        float h1[16], h2[16], h3[16];
#pragma unroll
        for (int j = 0; j < 16; j++)
            h1[j] = fmaxf(W1[2 * j] * feat0 + W1[2 * j + 1] * feat1 + b1[j], 0.0f);
#pragma unroll
        for (int j = 0; j < 16; j++) {
            float a = b2[j];
#pragma unroll
            for (int kk = 0; kk < 16; kk++) a += W2[j * 16 + kk] * h1[kk];
            h2[j] = fmaxf(a, 0.0f);
        }
#pragma unroll
        for (int j = 0; j < 16; j++) {
            float a = b3[j];
#pragma unroll
            for (int kk = 0; kk < 16; kk++) a += W3[j * 16 + kk] * h2[kk];
            h3[j] = fmaxf(a, 0.0f);
        }

        float dh3[16];
#pragma unroll
        for (int j = 0; j < 16; j++) dh3[j] = (h3[j] > 0.0f) ? W4[j] : 0.0f;

        float dh2[16];
#pragma unroll
        for (int kk = 0; kk < 16; kk++) {
            float a = 0.0f;
#pragma unroll
            for (int j = 0; j < 16; j++) a += W3[j * 16 + kk] * dh3[j];
            dh2[kk] = (h2[kk] > 0.0f) ? a : 0.0f;
        }

        float dfeat0 = 0.0f, dfeat1 = 0.0f;
#pragma unroll
        for (int kk = 0; kk < 16; kk++) {
            float a = 0.0f;
#pragma unroll
            for (int j = 0; j < 16; j++) a += W2[j * 16 + kk] * dh2[j];
            float dh1k = (h1[kk] > 0.0f) ? a : 0.0f;
            dfeat0 += W1[2 * kk] * dh1k;
            dfeat1 += W1[2 * kk + 1] * dh1k;
        }

        float half_sum  = 0.5f * (dfeat0 + dfeat1);
        float half_diff = 0.5f * (dfeat0 - dfeat1);
        float inv_delta = 1.0f / delta;
        float dtr  = half_sum + half_diff * tr * inv_delta * gate;
        float ddet = half_diff * (-2.0f) * inv_delta * gate;

        float S00 = 2.0f * (dtr + ddet * Cm11);
        float S11 = 2.0f * (dtr + ddet * Cm00);
        float S01 = -2.0f * ddet * Cm01;

        float dF00 = Fn00 * S00 + Fn01 * S01;
        float dF01 = Fn00 * S01 + Fn01 * S11;
        float dF10 = Fn10 * S00 + Fn11 * S01;
        float dF11 = Fn10 * S01 + Fn11 * S11;

        float a00 = STRESS_COEF * dF00 + P_MASSc * Ci.x;
        float a01 = STRESS_COEF * dF01 + P_MASSc * Ci.y;
        float a10 = STRESS_COEF * dF10 + P_MASSc * Ci.z;
        float a11 = STRESS_COEF * dF11 + P_MASSc * Ci.w;

        float pvx = P_MASSc * vi.x;
        float pvy = P_MASSc * vi.y;

        float px = xi.x * INV_DX, py = xi.y * INV_DX;
        int   bx = (int)floorf(px - 0.5f);
        int   by = (int)floorf(py - 0.5f);
        float fx = px - (float)bx;
        float fy = py - (float)by;
        float wxs[3] = {0.5f * (1.5f - fx) * (1.5f - fx),
                        0.75f - (fx - 1.0f) * (fx - 1.0f),
                        0.5f * (fx - 0.5f) * (fx - 0.5f)};
        float wys[3] = {0.5f * (1.5f - fy) * (1.5f - fy),
                        0.75f - (fy - 1.0f) * (fy - 1.0f),
                        0.5f * (fy - 0.5f) * (fy - 0.5f)};

        Fnew_out[i] = make_float4(Fn00, Fn01, Fn10, Fn11);

        int li0 = bx - ox;        // in [0,3]
        int lj0 = by - oy;

#pragma unroll
        for (int ii = 0; ii < 3; ii++) {
            float dxp = ((float)ii - fx) * DXc;
#pragma unroll
            for (int jj = 0; jj < 3; jj++) {
                float dyp = ((float)jj - fy) * DXc;
                float wt = wxs[ii] * wys[jj];
                int lidx = (li0 + ii) * 6 + (lj0 + jj);
                float momx = wt * (pvx + a00 * dxp + a01 * dyp);
                float momy = wt * (pvy + a10 * dxp + a11 * dyp);
                atomicAdd(&lacc[lidx],      momx);
                atomicAdd(&lacc[36 + lidx], momy);
                atomicAdd(&lacc[72 + lidx], wt * P_MASSc);
            }
        }
    }
    __syncthreads();

    if (threadIdx.x < 108) {
        int plane = threadIdx.x / 36;
        int lidx  = threadIdx.x % 36;
        int gi = ox + lidx / 6;
        int gj = oy + lidx % 6;
        float val = lacc[threadIdx.x];
        if (val != 0.0f)
            atomicAdd(&grid[plane * NCELL + gi * NGc + gj], val);
    }
}

// ---------------------------------------------------------------------------
// Grid: momentum -> velocity, gravity, boundaries
// ---------------------------------------------------------------------------
__global__ __launch_bounds__(256) void grid_kernel(
    const float* __restrict__ grid, float2* __restrict__ gv)
{
    int idx = blockIdx.x * 256 + threadIdx.x;
    if (idx >= NCELL) return;
    int i = idx >> 7;
    int j = idx & 127;

    float vx = grid[idx];
    float vy = grid[NCELL + idx];
    float m  = grid[2 * NCELL + idx];
    if (m > 0.0f) {
        float inv_m = 1.0f / m;
        vx *= inv_m;
        vy *= inv_m;
    }
    vy -= DTc * GRAV;
    if (i < 3)        vx = fmaxf(vx, 0.0f);
    if (i >= NGc - 3) vx = fminf(vx, 0.0f);
    if (j < 3)        vy = fmaxf(vy, 0.0f);
    if (j >= NGc - 3) vy = fminf(vy, 0.0f);

    gv[idx] = make_float2(vx, vy);
}

// ---------------------------------------------------------------------------
// G2P
// ---------------------------------------------------------------------------
__global__ __launch_bounds__(256) void g2p_kernel(
    const float2* __restrict__ x, const float2* __restrict__ v,
    const int* __restrict__ material, const float* __restrict__ Jp,
    const float2* __restrict__ gv,
    float2* __restrict__ out_x, float2* __restrict__ out_v,
    float4* __restrict__ out_C, float* __restrict__ out_mat,
    float* __restrict__ out_Jp, int n)
{
    int i = blockIdx.x * 256 + threadIdx.x;
    if (i >= n) return;

    float2 xi = x[i];
    float2 vi = v[i];

    float px = xi.x * INV_DX, py = xi.y * INV_DX;
    int   bx = (int)floorf(px - 0.5f);
    int   by = (int)floorf(py - 0.5f);
    float fx = px - (float)bx;
    float fy = py - (float)by;
    float wxs[3] = {0.5f * (1.5f - fx) * (1.5f - fx),
                    0.75f - (fx - 1.0f) * (fx - 1.0f),
                    0.5f * (fx - 0.5f) * (fx - 0.5f)};
    float wys[3] = {0.5f * (1.5f - fy) * (1.5f - fy),
                    0.75f - (fy - 1.0f) * (fy - 1.0f),
                    0.5f * (fy - 0.5f) * (fy - 0.5f)};

    float accvx = 0.0f, accvy = 0.0f;
    float accC00 = 0.0f, accC01 = 0.0f, accC10 = 0.0f, accC11 = 0.0f;

#pragma unroll
    for (int ii = 0; ii < 3; ii++) {
        float gxx = (float)(bx + ii) * DXc;
#pragma unroll
        for (int jj = 0; jj < 3; jj++) {
            float wt = wxs[ii] * wys[jj];
            float2 gvn = gv[(bx + ii) * NGc + (by + jj)];
            float gxy = (float)(by + jj) * DXc;
            accvx  += wt * gvn.x;
            accvy  += wt * gvn.y;
            accC00 += wt * gvn.x * gxx;
            accC01 += wt * gvn.x * gxy;
            accC10 += wt * gvn.y * gxx;
            accC11 += wt * gvn.y * gxy;
        }
    }

    const float k4 = 4.0f * INV_DX * INV_DX;
    out_x[i]   = make_float2(xi.x + DTc * vi.x, xi.y + DTc * vi.y);
    out_v[i]   = make_float2(accvx, accvy);
    out_C[i]   = make_float4(k4 * (accC00 - accvx * xi.x),
                             k4 * (accC01 - accvx * xi.y),
                             k4 * (accC10 - accvy * xi.x),
                             k4 * (accC11 - accvy * xi.y));
    out_mat[i] = (float)material[i];
    out_Jp[i]  = Jp[i];
}

// ---------------------------------------------------------------------------
extern "C" void kernel_launch(void* const* d_in, const int* in_sizes, int n_in,
                              void* d_out, int out_size, void* d_ws, size_t ws_size,
                              hipStream_t stream)
{
    const float2* x  = (const float2*)d_in[0];
    const float2* v  = (const float2*)d_in[1];
    const float4* C  = (const float4*)d_in[2];
    const float4* F  = (const float4*)d_in[3];
    const int* material = (const int*)d_in[4];
    const float* Jp  = (const float*)d_in[5];
    const float* W1  = (const float*)d_in[8];
    const float* b1  = (const float*)d_in[9];
    const float* W2  = (const float*)d_in[10];
    const float* b2  = (const float*)d_in[11];
    const float* W3  = (const float*)d_in[12];
    const float* b3  = (const float*)d_in[13];
    const float* W4  = (const float*)d_in[14];

    const int n = in_sizes[0] / 2;

    // workspace layout
    float*    grid   = (float*)d_ws;                         // 3*NCELL floats
    unsigned* gcnt   = (unsigned*)(grid + 3 * NCELL);        // NBIN
    unsigned* binoff = gcnt + NBIN;                          // NBIN
    float2*   gv     = (float2*)(binoff + NBIN);             // NCELL float2

    // sort scratch lives in the out_mat/out_Jp regions (overwritten by g2p last)
    float* out = (float*)d_out;
    float2* out_x   = (float2*)out;
    float2* out_v   = (float2*)(out + 2 * (size_t)n);
    float4* out_C   = (float4*)(out + 4 * (size_t)n);
    float4* out_F   = (float4*)(out + 8 * (size_t)n);
    float*  out_mat = out + 12 * (size_t)n;
    float*  out_Jp  = out + 13 * (size_t)n;
    unsigned* key       = (unsigned*)out_mat;   // N u32 scratch
    unsigned* sortedIdx = (unsigned*)out_Jp;    // N u32 scratch

    hipMemsetAsync(d_ws, 0, (3 * NCELL + NBIN) * sizeof(float), stream);

    int s1_blocks = (n + S1_BLK * S1_PPT - 1) / (S1_BLK * S1_PPT);
    bin_kernel<<<s1_blocks, S1_BLK, 0, stream>>>(x, key, gcnt, n);
    scan_kernel<<<1, NBIN, 0, stream>>>(gcnt, binoff);
    scatter_kernel<<<(n + 255) / 256, 256, 0, stream>>>(key, binoff, sortedIdx, n);
    p2g_kernel<<<NBIN, 256, 0, stream>>>(x, v, C, F, W1, b1, W2, b2, W3, b3, W4,
                                         gcnt, binoff, sortedIdx, grid, (float4*)out_F);
    grid_kernel<<<(NCELL + 255) / 256, 256, 0, stream>>>(grid, gv);
    g2p_kernel<<<(n + 255) / 256, 256, 0, stream>>>(x, v, material, Jp, gv,
                                                    out_x, out_v, out_C, out_mat, out_Jp, n);
}

// Round 4
// 464.184 us; speedup vs baseline: 8.1940x; 1.0984x over previous
//
#include <hip/hip_runtime.h>
#include <math.h>

constexpr int   NGc    = 128;
constexpr int   NCELL  = NGc * NGc;
constexpr int   NTILE  = 32;                // 32x32 tiles of 4x4 cells
constexpr int   NBIN   = NTILE * NTILE;     // 1024
constexpr float DTc    = 1e-4f;
constexpr float DXc    = 1.0f / 128.0f;
constexpr float INV_DX = 128.0f;
constexpr float P_VOLc = (DXc * 0.5f) * (DXc * 0.5f);
constexpr float P_MASSc = P_VOLc * 1.0f;
constexpr float GRAV   = 9.8f;
constexpr float STRESS_COEF = -DTc * P_VOLc * 4.0f * INV_DX * INV_DX;

// ---------------------------------------------------------------------------
// S1: per-block LDS histogram + local rank -> key = tile<<20 | pos_in_bin
// ---------------------------------------------------------------------------
constexpr int S1_PPT = 8;
constexpr int S1_BLK = 1024;

__global__ __launch_bounds__(1024) void bin_kernel(
    const float2* __restrict__ x, unsigned* __restrict__ key,
    unsigned* __restrict__ gcnt, int n)
{
    __shared__ unsigned hist[NBIN];
    hist[threadIdx.x] = 0;
    __syncthreads();

    int base_i = blockIdx.x * (S1_BLK * S1_PPT);
    unsigned t_arr[S1_PPT], r_arr[S1_PPT];
#pragma unroll
    for (int k = 0; k < S1_PPT; k++) {
        int i = base_i + k * S1_BLK + threadIdx.x;
        unsigned t = 0, r = 0;
        if (i < n) {
            float2 xi = x[i];
            int bx = (int)floorf(xi.x * INV_DX - 0.5f);
            int by = (int)floorf(xi.y * INV_DX - 0.5f);
            t = (unsigned)((bx >> 2) * NTILE + (by >> 2));
            r = atomicAdd(&hist[t], 1u);
        }
        t_arr[k] = t; r_arr[k] = r;
    }
    __syncthreads();

    unsigned c = hist[threadIdx.x];
    __syncthreads();
    hist[threadIdx.x] = c ? atomicAdd(&gcnt[threadIdx.x], c) : 0u;
    __syncthreads();

#pragma unroll
    for (int k = 0; k < S1_PPT; k++) {
        int i = base_i + k * S1_BLK + threadIdx.x;
        if (i < n)
            key[i] = (t_arr[k] << 20) | (hist[t_arr[k]] + r_arr[k]);
    }
}

// ---------------------------------------------------------------------------
// S2: exclusive scan over 1024 bin counts
// ---------------------------------------------------------------------------
__global__ __launch_bounds__(1024) void scan_kernel(
    const unsigned* __restrict__ gcnt, unsigned* __restrict__ binoff)
{
    __shared__ unsigned s[NBIN];
    unsigned v = gcnt[threadIdx.x];
    s[threadIdx.x] = v;
    __syncthreads();
    for (int d = 1; d < NBIN; d <<= 1) {
        unsigned add = (threadIdx.x >= (unsigned)d) ? s[threadIdx.x - d] : 0u;
        __syncthreads();
        s[threadIdx.x] += add;
        __syncthreads();
    }
    binoff[threadIdx.x] = s[threadIdx.x] - v;
}

// ---------------------------------------------------------------------------
// Stage A: coalesced per-particle NN stress; scatter packed 32B record
//   rec = {x, y, a00, a01, a10, a11, pvx, pvy} to sorted slot.
// ---------------------------------------------------------------------------
__global__ __launch_bounds__(256) void stagea_kernel(
    const float2* __restrict__ x, const float2* __restrict__ v,
    const float4* __restrict__ C, const float4* __restrict__ F,
    const float* __restrict__ W1, const float* __restrict__ b1,
    const float* __restrict__ W2, const float* __restrict__ b2,
    const float* __restrict__ W3, const float* __restrict__ b3,
    const float* __restrict__ W4,
    const unsigned* __restrict__ key, const unsigned* __restrict__ binoff,
    float4* __restrict__ recs, int n)
{
    int i = blockIdx.x * 256 + threadIdx.x;
    if (i >= n) return;

    float2 xi = x[i];
    float2 vi = v[i];
    float4 Ci = C[i];
    float4 Fi = F[i];

    float Fn00 = Fi.x + DTc * (Ci.x * Fi.x + Ci.y * Fi.z);
    float Fn01 = Fi.y + DTc * (Ci.x * Fi.y + Ci.y * Fi.w);
    float Fn10 = Fi.z + DTc * (Ci.z * Fi.x + Ci.w * Fi.z);
    float Fn11 = Fi.w + DTc * (Ci.z * Fi.y + Ci.w * Fi.w);

    float Cm00 = Fn00 * Fn00 + Fn10 * Fn10;
    float Cm01 = Fn00 * Fn01 + Fn10 * Fn11;
    float Cm11 = Fn01 * Fn01 + Fn11 * Fn11;

    float tr  = Cm00 + Cm11;
    float det = Cm00 * Cm11 - Cm01 * Cm01;
    float g   = tr * tr - 4.0f * det;
    float gate = (g > 1e-8f) ? 1.0f : 0.0f;
    float delta = sqrtf(fmaxf(g, 1e-8f));
    float feat0 = 0.5f * (tr + delta);
    float feat1 = 0.5f * (tr - delta);

    float h1[16], h2[16], h3[16];
#pragma unroll
    for (int j = 0; j < 16; j++)
        h1[j] = fmaxf(W1[2 * j] * feat0 + W1[2 * j + 1] * feat1 + b1[j], 0.0f);
#pragma unroll
    for (int j = 0; j < 16; j++) {
        float a = b2[j];
#pragma unroll
        for (int kk = 0; kk < 16; kk++) a += W2[j * 16 + kk] * h1[kk];
        h2[j] = fmaxf(a, 0.0f);
    }
#pragma unroll
    for (int j = 0; j < 16; j++) {
        float a = b3[j];
#pragma unroll
        for (int kk = 0; kk < 16; kk++) a += W3[j * 16 + kk] * h2[kk];
        h3[j] = fmaxf(a, 0.0f);
    }

    float dh3[16];
#pragma unroll
    for (int j = 0; j < 16; j++) dh3[j] = (h3[j] > 0.0f) ? W4[j] : 0.0f;

    float dh2[16];
#pragma unroll
    for (int kk = 0; kk < 16; kk++) {
        float a = 0.0f;
#pragma unroll
        for (int j = 0; j < 16; j++) a += W3[j * 16 + kk] * dh3[j];
        dh2[kk] = (h2[kk] > 0.0f) ? a : 0.0f;
    }

    float dfeat0 = 0.0f, dfeat1 = 0.0f;
#pragma unroll
    for (int kk = 0; kk < 16; kk++) {
        float a = 0.0f;
#pragma unroll
        for (int j = 0; j < 16; j++) a += W2[j * 16 + kk] * dh2[j];
        float dh1k = (h1[kk] > 0.0f) ? a : 0.0f;
        dfeat0 += W1[2 * kk] * dh1k;
        dfeat1 += W1[2 * kk + 1] * dh1k;
    }

    float half_sum  = 0.5f * (dfeat0 + dfeat1);
    float half_diff = 0.5f * (dfeat0 - dfeat1);
    float inv_delta = 1.0f / delta;
    float dtr  = half_sum + half_diff * tr * inv_delta * gate;
    float ddet = half_diff * (-2.0f) * inv_delta * gate;

    float S00 = 2.0f * (dtr + ddet * Cm11);
    float S11 = 2.0f * (dtr + ddet * Cm00);
    float S01 = -2.0f * ddet * Cm01;

    float dF00 = Fn00 * S00 + Fn01 * S01;
    float dF01 = Fn00 * S01 + Fn01 * S11;
    float dF10 = Fn10 * S00 + Fn11 * S01;
    float dF11 = Fn10 * S01 + Fn11 * S11;

    float a00 = STRESS_COEF * dF00 + P_MASSc * Ci.x;
    float a01 = STRESS_COEF * dF01 + P_MASSc * Ci.y;
    float a10 = STRESS_COEF * dF10 + P_MASSc * Ci.z;
    float a11 = STRESS_COEF * dF11 + P_MASSc * Ci.w;

    unsigned k = key[i];
    unsigned pos = binoff[k >> 20] + (k & 0xFFFFFu);

    recs[2 * (size_t)pos]     = make_float4(xi.x, xi.y, a00, a01);
    recs[2 * (size_t)pos + 1] = make_float4(a10, a11, P_MASSc * vi.x, P_MASSc * vi.y);
}

// ---------------------------------------------------------------------------
// Stage B: per-tile coalesced record stream -> LDS accumulate -> halo merge
// ---------------------------------------------------------------------------
__global__ __launch_bounds__(256) void p2g_kernel(
    const float4* __restrict__ recs,
    const unsigned* __restrict__ gcnt, const unsigned* __restrict__ binoff,
    float* __restrict__ grid)
{
    int t = blockIdx.x;
    int cnt = (int)gcnt[t];
    if (cnt == 0) return;
    int base = (int)binoff[t];
    int ox = (t >> 5) << 2;
    int oy = (t & 31) << 2;

    __shared__ float lacc[3 * 36];
    if (threadIdx.x < 108) lacc[threadIdx.x] = 0.0f;
    __syncthreads();

    for (int k = threadIdx.x; k < cnt; k += 256) {
        float4 r0 = recs[2 * (size_t)(base + k)];
        float4 r1 = recs[2 * (size_t)(base + k) + 1];
        float a00 = r0.z, a01 = r0.w, a10 = r1.x, a11 = r1.y;
        float pvx = r1.z, pvy = r1.w;

        float px = r0.x * INV_DX, py = r0.y * INV_DX;
        int   bx = (int)floorf(px - 0.5f);
        int   by = (int)floorf(py - 0.5f);
        float fx = px - (float)bx;
        float fy = py - (float)by;
        float wxs[3] = {0.5f * (1.5f - fx) * (1.5f - fx),
                        0.75f - (fx - 1.0f) * (fx - 1.0f),
                        0.5f * (fx - 0.5f) * (fx - 0.5f)};
        float wys[3] = {0.5f * (1.5f - fy) * (1.5f - fy),
                        0.75f - (fy - 1.0f) * (fy - 1.0f),
                        0.5f * (fy - 0.5f) * (fy - 0.5f)};

        int li0 = bx - ox;
        int lj0 = by - oy;

#pragma unroll
        for (int ii = 0; ii < 3; ii++) {
            float dxp = ((float)ii - fx) * DXc;
#pragma unroll
            for (int jj = 0; jj < 3; jj++) {
                float dyp = ((float)jj - fy) * DXc;
                float wt = wxs[ii] * wys[jj];
                int lidx = (li0 + ii) * 6 + (lj0 + jj);
                atomicAdd(&lacc[lidx],      wt * (pvx + a00 * dxp + a01 * dyp));
                atomicAdd(&lacc[36 + lidx], wt * (pvy + a10 * dxp + a11 * dyp));
                atomicAdd(&lacc[72 + lidx], wt * P_MASSc);
            }
        }
    }
    __syncthreads();

    if (threadIdx.x < 108) {
        int plane = threadIdx.x / 36;
        int lidx  = threadIdx.x % 36;
        int gi = ox + lidx / 6;
        int gj = oy + lidx % 6;
        float val = lacc[threadIdx.x];
        if (val != 0.0f)
            atomicAdd(&grid[plane * NCELL + gi * NGc + gj], val);
    }
}

// ---------------------------------------------------------------------------
// Grid: momentum -> velocity, gravity, boundaries
// ---------------------------------------------------------------------------
__global__ __launch_bounds__(256) void grid_kernel(
    const float* __restrict__ grid, float2* __restrict__ gv)
{
    int idx = blockIdx.x * 256 + threadIdx.x;
    if (idx >= NCELL) return;
    int i = idx >> 7;
    int j = idx & 127;

    float vx = grid[idx];
    float vy = grid[NCELL + idx];
    float m  = grid[2 * NCELL + idx];
    if (m > 0.0f) {
        float inv_m = 1.0f / m;
        vx *= inv_m;
        vy *= inv_m;
    }
    vy -= DTc * GRAV;
    if (i < 3)        vx = fmaxf(vx, 0.0f);
    if (i >= NGc - 3) vx = fminf(vx, 0.0f);
    if (j < 3)        vy = fmaxf(vy, 0.0f);
    if (j >= NGc - 3) vy = fminf(vy, 0.0f);

    gv[idx] = make_float2(vx, vy);
}

// ---------------------------------------------------------------------------
// G2P (+ Fnew recompute and write, coalesced)
// ---------------------------------------------------------------------------
__global__ __launch_bounds__(256) void g2p_kernel(
    const float2* __restrict__ x, const float2* __restrict__ v,
    const float4* __restrict__ C, const float4* __restrict__ F,
    const int* __restrict__ material, const float* __restrict__ Jp,
    const float2* __restrict__ gv,
    float2* __restrict__ out_x, float2* __restrict__ out_v,
    float4* __restrict__ out_C, float4* __restrict__ out_F,
    float* __restrict__ out_mat, float* __restrict__ out_Jp, int n)
{
    int i = blockIdx.x * 256 + threadIdx.x;
    if (i >= n) return;

    float2 xi = x[i];
    float2 vi = v[i];
    float4 Ci = C[i];
    float4 Fi = F[i];

    float Fn00 = Fi.x + DTc * (Ci.x * Fi.x + Ci.y * Fi.z);
    float Fn01 = Fi.y + DTc * (Ci.x * Fi.y + Ci.y * Fi.w);
    float Fn10 = Fi.z + DTc * (Ci.z * Fi.x + Ci.w * Fi.z);
    float Fn11 = Fi.w + DTc * (Ci.z * Fi.y + Ci.w * Fi.w);

    float px = xi.x * INV_DX, py = xi.y * INV_DX;
    int   bx = (int)floorf(px - 0.5f);
    int   by = (int)floorf(py - 0.5f);
    float fx = px - (float)bx;
    float fy = py - (float)by;
    float wxs[3] = {0.5f * (1.5f - fx) * (1.5f - fx),
                    0.75f - (fx - 1.0f) * (fx - 1.0f),
                    0.5f * (fx - 0.5f) * (fx - 0.5f)};
    float wys[3] = {0.5f * (1.5f - fy) * (1.5f - fy),
                    0.75f - (fy - 1.0f) * (fy - 1.0f),
                    0.5f * (fy - 0.5f) * (fy - 0.5f)};

    float accvx = 0.0f, accvy = 0.0f;
    float accC00 = 0.0f, accC01 = 0.0f, accC10 = 0.0f, accC11 = 0.0f;

#pragma unroll
    for (int ii = 0; ii < 3; ii++) {
        float gxx = (float)(bx + ii) * DXc;
#pragma unroll
        for (int jj = 0; jj < 3; jj++) {
            float wt = wxs[ii] * wys[jj];
            float2 gvn = gv[(bx + ii) * NGc + (by + jj)];
            float gxy = (float)(by + jj) * DXc;
            accvx  += wt * gvn.x;
            accvy  += wt * gvn.y;
            accC00 += wt * gvn.x * gxx;
            accC01 += wt * gvn.x * gxy;
            accC10 += wt * gvn.y * gxx;
            accC11 += wt * gvn.y * gxy;
        }
    }

    const float k4 = 4.0f * INV_DX * INV_DX;
    out_x[i]   = make_float2(xi.x + DTc * vi.x, xi.y + DTc * vi.y);
    out_v[i]   = make_float2(accvx, accvy);
    out_C[i]   = make_float4(k4 * (accC00 - accvx * xi.x),
                             k4 * (accC01 - accvx * xi.y),
                             k4 * (accC10 - accvy * xi.x),
                             k4 * (accC11 - accvy * xi.y));
    out_F[i]   = make_float4(Fn00, Fn01, Fn10, Fn11);
    out_mat[i] = (float)material[i];
    out_Jp[i]  = Jp[i];
}

// ---------------------------------------------------------------------------
extern "C" void kernel_launch(void* const* d_in, const int* in_sizes, int n_in,
                              void* d_out, int out_size, void* d_ws, size_t ws_size,
                              hipStream_t stream)
{
    const float2* x  = (const float2*)d_in[0];
    const float2* v  = (const float2*)d_in[1];
    const float4* C  = (const float4*)d_in[2];
    const float4* F  = (const float4*)d_in[3];
    const int* material = (const int*)d_in[4];
    const float* Jp  = (const float*)d_in[5];
    const float* W1  = (const float*)d_in[8];
    const float* b1  = (const float*)d_in[9];
    const float* W2  = (const float*)d_in[10];
    const float* b2  = (const float*)d_in[11];
    const float* W3  = (const float*)d_in[12];
    const float* b3  = (const float*)d_in[13];
    const float* W4  = (const float*)d_in[14];

    const int n = in_sizes[0] / 2;

    // d_ws: grid (3*NCELL) + gcnt (NBIN) + binoff (NBIN) + gv (NCELL float2)
    float*    grid   = (float*)d_ws;
    unsigned* gcnt   = (unsigned*)(grid + 3 * NCELL);
    unsigned* binoff = gcnt + NBIN;
    float2*   gv     = (float2*)(binoff + NBIN);

    float* out = (float*)d_out;
    float2* out_x   = (float2*)out;                    // 0..2N
    float2* out_v   = (float2*)(out + 2 * (size_t)n);  // 2N..4N
    float4* out_C   = (float4*)(out + 4 * (size_t)n);  // 4N..8N
    float4* out_F   = (float4*)(out + 8 * (size_t)n);  // 8N..12N
    float*  out_mat = out + 12 * (size_t)n;            // 12N..13N
    float*  out_Jp  = out + 13 * (size_t)n;            // 13N..14N

    // middle-phase scratch inside d_out (consumed before g2p overwrites):
    float4*   recs = (float4*)(out + 2 * (size_t)n);   // 8N floats: 2N..10N
    unsigned* key  = (unsigned*)out_mat;               // N u32:     12N..13N

    hipMemsetAsync(d_ws, 0, (3 * NCELL + NBIN) * sizeof(float), stream);

    int s1_blocks = (n + S1_BLK * S1_PPT - 1) / (S1_BLK * S1_PPT);
    int blocks    = (n + 255) / 256;
    bin_kernel<<<s1_blocks, S1_BLK, 0, stream>>>(x, key, gcnt, n);
    scan_kernel<<<1, NBIN, 0, stream>>>(gcnt, binoff);
    stagea_kernel<<<blocks, 256, 0, stream>>>(x, v, C, F, W1, b1, W2, b2, W3, b3, W4,
                                              key, binoff, recs, n);
    p2g_kernel<<<NBIN, 256, 0, stream>>>(recs, gcnt, binoff, grid);
    grid_kernel<<<(NCELL + 255) / 256, 256, 0, stream>>>(grid, gv);
    g2p_kernel<<<blocks, 256, 0, stream>>>(x, v, C, F, material, Jp, gv,
                                           out_x, out_v, out_C, out_F, out_mat, out_Jp, n);
}

// Round 5
// 452.870 us; speedup vs baseline: 8.3987x; 1.0250x over previous
//
#include <hip/hip_runtime.h>
#include <math.h>

constexpr int   NGc    = 128;
constexpr int   NCELL  = NGc * NGc;
constexpr int   NTILE  = 32;                // 32x32 tiles of 4x4 cells
constexpr int   NBIN   = NTILE * NTILE;     // 1024
constexpr int   MAXCH  = 8;                 // chunks of 256 per tile (covers cnt<=2048; last chunk loops)
constexpr float DTc    = 1e-4f;
constexpr float DXc    = 1.0f / 128.0f;
constexpr float INV_DX = 128.0f;
constexpr float P_VOLc = (DXc * 0.5f) * (DXc * 0.5f);
constexpr float P_MASSc = P_VOLc * 1.0f;
constexpr float GRAV   = 9.8f;
constexpr float STRESS_COEF = -DTc * P_VOLc * 4.0f * INV_DX * INV_DX;

// ---------------------------------------------------------------------------
// S1: per-block LDS histogram + local rank -> key = tile<<20 | pos_in_bin
// ---------------------------------------------------------------------------
constexpr int S1_PPT = 8;
constexpr int S1_BLK = 1024;

__global__ __launch_bounds__(1024) void bin_kernel(
    const float2* __restrict__ x, unsigned* __restrict__ key,
    unsigned* __restrict__ gcnt, int n)
{
    __shared__ unsigned hist[NBIN];
    hist[threadIdx.x] = 0;
    __syncthreads();

    int base_i = blockIdx.x * (S1_BLK * S1_PPT);
    unsigned t_arr[S1_PPT], r_arr[S1_PPT];
#pragma unroll
    for (int k = 0; k < S1_PPT; k++) {
        int i = base_i + k * S1_BLK + threadIdx.x;
        unsigned t = 0, r = 0;
        if (i < n) {
            float2 xi = x[i];
            int bx = (int)floorf(xi.x * INV_DX - 0.5f);
            int by = (int)floorf(xi.y * INV_DX - 0.5f);
            t = (unsigned)((bx >> 2) * NTILE + (by >> 2));
            r = atomicAdd(&hist[t], 1u);
        }
        t_arr[k] = t; r_arr[k] = r;
    }
    __syncthreads();

    unsigned c = hist[threadIdx.x];
    __syncthreads();
    hist[threadIdx.x] = c ? atomicAdd(&gcnt[threadIdx.x], c) : 0u;
    __syncthreads();

#pragma unroll
    for (int k = 0; k < S1_PPT; k++) {
        int i = base_i + k * S1_BLK + threadIdx.x;
        if (i < n)
            key[i] = (t_arr[k] << 20) | (hist[t_arr[k]] + r_arr[k]);
    }
}

// ---------------------------------------------------------------------------
// S2: exclusive scan over 1024 bin counts
// ---------------------------------------------------------------------------
__global__ __launch_bounds__(1024) void scan_kernel(
    const unsigned* __restrict__ gcnt, unsigned* __restrict__ binoff)
{
    __shared__ unsigned s[NBIN];
    unsigned v = gcnt[threadIdx.x];
    s[threadIdx.x] = v;
    __syncthreads();
    for (int d = 1; d < NBIN; d <<= 1) {
        unsigned add = (threadIdx.x >= (unsigned)d) ? s[threadIdx.x - d] : 0u;
        __syncthreads();
        s[threadIdx.x] += add;
        __syncthreads();
    }
    binoff[threadIdx.x] = s[threadIdx.x] - v;
}

// ---------------------------------------------------------------------------
// Stage A: coalesced per-particle NN stress; scatter packed 32B record
//   rec = {x, y, a00, a01, a10, a11, pvx, pvy} to sorted slot.
// ---------------------------------------------------------------------------
__global__ __launch_bounds__(256) void stagea_kernel(
    const float2* __restrict__ x, const float2* __restrict__ v,
    const float4* __restrict__ C, const float4* __restrict__ F,
    const float* __restrict__ W1, const float* __restrict__ b1,
    const float* __restrict__ W2, const float* __restrict__ b2,
    const float* __restrict__ W3, const float* __restrict__ b3,
    const float* __restrict__ W4,
    const unsigned* __restrict__ key, const unsigned* __restrict__ binoff,
    float4* __restrict__ recs, int n)
{
    int i = blockIdx.x * 256 + threadIdx.x;
    if (i >= n) return;

    float2 xi = x[i];
    float2 vi = v[i];
    float4 Ci = C[i];
    float4 Fi = F[i];

    float Fn00 = Fi.x + DTc * (Ci.x * Fi.x + Ci.y * Fi.z);
    float Fn01 = Fi.y + DTc * (Ci.x * Fi.y + Ci.y * Fi.w);
    float Fn10 = Fi.z + DTc * (Ci.z * Fi.x + Ci.w * Fi.z);
    float Fn11 = Fi.w + DTc * (Ci.z * Fi.y + Ci.w * Fi.w);

    float Cm00 = Fn00 * Fn00 + Fn10 * Fn10;
    float Cm01 = Fn00 * Fn01 + Fn10 * Fn11;
    float Cm11 = Fn01 * Fn01 + Fn11 * Fn11;

    float tr  = Cm00 + Cm11;
    float det = Cm00 * Cm11 - Cm01 * Cm01;
    float g   = tr * tr - 4.0f * det;
    float gate = (g > 1e-8f) ? 1.0f : 0.0f;
    float delta = sqrtf(fmaxf(g, 1e-8f));
    float feat0 = 0.5f * (tr + delta);
    float feat1 = 0.5f * (tr - delta);

    float h1[16], h2[16], h3[16];
#pragma unroll
    for (int j = 0; j < 16; j++)
        h1[j] = fmaxf(W1[2 * j] * feat0 + W1[2 * j + 1] * feat1 + b1[j], 0.0f);
#pragma unroll
    for (int j = 0; j < 16; j++) {
        float a = b2[j];
#pragma unroll
        for (int kk = 0; kk < 16; kk++) a += W2[j * 16 + kk] * h1[kk];
        h2[j] = fmaxf(a, 0.0f);
    }
#pragma unroll
    for (int j = 0; j < 16; j++) {
        float a = b3[j];
#pragma unroll
        for (int kk = 0; kk < 16; kk++) a += W3[j * 16 + kk] * h2[kk];
        h3[j] = fmaxf(a, 0.0f);
    }

    float dh3[16];
#pragma unroll
    for (int j = 0; j < 16; j++) dh3[j] = (h3[j] > 0.0f) ? W4[j] : 0.0f;

    float dh2[16];
#pragma unroll
    for (int kk = 0; kk < 16; kk++) {
        float a = 0.0f;
#pragma unroll
        for (int j = 0; j < 16; j++) a += W3[j * 16 + kk] * dh3[j];
        dh2[kk] = (h2[kk] > 0.0f) ? a : 0.0f;
    }

    float dfeat0 = 0.0f, dfeat1 = 0.0f;
#pragma unroll
    for (int kk = 0; kk < 16; kk++) {
        float a = 0.0f;
#pragma unroll
        for (int j = 0; j < 16; j++) a += W2[j * 16 + kk] * dh2[j];
        float dh1k = (h1[kk] > 0.0f) ? a : 0.0f;
        dfeat0 += W1[2 * kk] * dh1k;
        dfeat1 += W1[2 * kk + 1] * dh1k;
    }

    float half_sum  = 0.5f * (dfeat0 + dfeat1);
    float half_diff = 0.5f * (dfeat0 - dfeat1);
    float inv_delta = 1.0f / delta;
    float dtr  = half_sum + half_diff * tr * inv_delta * gate;
    float ddet = half_diff * (-2.0f) * inv_delta * gate;

    float S00 = 2.0f * (dtr + ddet * Cm11);
    float S11 = 2.0f * (dtr + ddet * Cm00);
    float S01 = -2.0f * ddet * Cm01;

    float dF00 = Fn00 * S00 + Fn01 * S01;
    float dF01 = Fn00 * S01 + Fn01 * S11;
    float dF10 = Fn10 * S00 + Fn11 * S01;
    float dF11 = Fn10 * S01 + Fn11 * S11;

    float a00 = STRESS_COEF * dF00 + P_MASSc * Ci.x;
    float a01 = STRESS_COEF * dF01 + P_MASSc * Ci.y;
    float a10 = STRESS_COEF * dF10 + P_MASSc * Ci.z;
    float a11 = STRESS_COEF * dF11 + P_MASSc * Ci.w;

    unsigned k = key[i];
    unsigned pos = binoff[k >> 20] + (k & 0xFFFFFu);

    recs[2 * (size_t)pos]     = make_float4(xi.x, xi.y, a00, a01);
    recs[2 * (size_t)pos + 1] = make_float4(a10, a11, P_MASSc * vi.x, P_MASSc * vi.y);
}

// ---------------------------------------------------------------------------
// Stage B (chunk-parallel): block = (tile, chunk of 256 particles).
// One accumulate round into LDS, then 108 global atomics.
// ---------------------------------------------------------------------------
__global__ __launch_bounds__(256) void p2g_kernel(
    const float4* __restrict__ recs,
    const unsigned* __restrict__ gcnt, const unsigned* __restrict__ binoff,
    float* __restrict__ grid)
{
    int t  = blockIdx.x >> 3;        // tile
    int ch = blockIdx.x & 7;         // chunk
    int cnt = (int)gcnt[t];
    int start = ch * 256;
    if (start >= cnt) return;
    int base = (int)binoff[t];
    int ox = (t >> 5) << 2;
    int oy = (t & 31) << 2;

    __shared__ float lacc[3 * 36];
    if (threadIdx.x < 108) lacc[threadIdx.x] = 0.0f;
    __syncthreads();

    // normally exactly one iteration; last chunk sweeps any overflow (>2048)
    int kend = (ch == MAXCH - 1) ? cnt : min(cnt, start + 256);
    for (int k = start + threadIdx.x; k < kend; k += 256) {
        float4 r0 = recs[2 * (size_t)(base + k)];
        float4 r1 = recs[2 * (size_t)(base + k) + 1];
        float a00 = r0.z, a01 = r0.w, a10 = r1.x, a11 = r1.y;
        float pvx = r1.z, pvy = r1.w;

        float px = r0.x * INV_DX, py = r0.y * INV_DX;
        int   bx = (int)floorf(px - 0.5f);
        int   by = (int)floorf(py - 0.5f);
        float fx = px - (float)bx;
        float fy = py - (float)by;
        float wxs[3] = {0.5f * (1.5f - fx) * (1.5f - fx),
                        0.75f - (fx - 1.0f) * (fx - 1.0f),
                        0.5f * (fx - 0.5f) * (fx - 0.5f)};
        float wys[3] = {0.5f * (1.5f - fy) * (1.5f - fy),
                        0.75f - (fy - 1.0f) * (fy - 1.0f),
                        0.5f * (fy - 0.5f) * (fy - 0.5f)};

        int li0 = bx - ox;
        int lj0 = by - oy;

#pragma unroll
        for (int ii = 0; ii < 3; ii++) {
            float dxp = ((float)ii - fx) * DXc;
#pragma unroll
            for (int jj = 0; jj < 3; jj++) {
                float dyp = ((float)jj - fy) * DXc;
                float wt = wxs[ii] * wys[jj];
                int lidx = (li0 + ii) * 6 + (lj0 + jj);
                atomicAdd(&lacc[lidx],      wt * (pvx + a00 * dxp + a01 * dyp));
                atomicAdd(&lacc[36 + lidx], wt * (pvy + a10 * dxp + a11 * dyp));
                atomicAdd(&lacc[72 + lidx], wt * P_MASSc);
            }
        }
    }
    __syncthreads();

    if (threadIdx.x < 108) {
        int plane = threadIdx.x / 36;
        int lidx  = threadIdx.x % 36;
        int gi = ox + lidx / 6;
        int gj = oy + lidx % 6;
        float val = lacc[threadIdx.x];
        if (val != 0.0f)
            atomicAdd(&grid[plane * NCELL + gi * NGc + gj], val);
    }
}

// ---------------------------------------------------------------------------
// Grid: momentum -> velocity, gravity, boundaries
// ---------------------------------------------------------------------------
__global__ __launch_bounds__(256) void grid_kernel(
    const float* __restrict__ grid, float2* __restrict__ gv)
{
    int idx = blockIdx.x * 256 + threadIdx.x;
    if (idx >= NCELL) return;
    int i = idx >> 7;
    int j = idx & 127;

    float vx = grid[idx];
    float vy = grid[NCELL + idx];
    float m  = grid[2 * NCELL + idx];
    if (m > 0.0f) {
        float inv_m = 1.0f / m;
        vx *= inv_m;
        vy *= inv_m;
    }
    vy -= DTc * GRAV;
    if (i < 3)        vx = fmaxf(vx, 0.0f);
    if (i >= NGc - 3) vx = fminf(vx, 0.0f);
    if (j < 3)        vy = fmaxf(vy, 0.0f);
    if (j >= NGc - 3) vy = fminf(vy, 0.0f);

    gv[idx] = make_float2(vx, vy);
}

// ---------------------------------------------------------------------------
// G2P (+ Fnew recompute and write, coalesced)
// ---------------------------------------------------------------------------
__global__ __launch_bounds__(256) void g2p_kernel(
    const float2* __restrict__ x, const float2* __restrict__ v,
    const float4* __restrict__ C, const float4* __restrict__ F,
    const int* __restrict__ material, const float* __restrict__ Jp,
    const float2* __restrict__ gv,
    float2* __restrict__ out_x, float2* __restrict__ out_v,
    float4* __restrict__ out_C, float4* __restrict__ out_F,
    float* __restrict__ out_mat, float* __restrict__ out_Jp, int n)
{
    int i = blockIdx.x * 256 + threadIdx.x;
    if (i >= n) return;

    float2 xi = x[i];
    float2 vi = v[i];
    float4 Ci = C[i];
    float4 Fi = F[i];

    float Fn00 = Fi.x + DTc * (Ci.x * Fi.x + Ci.y * Fi.z);
    float Fn01 = Fi.y + DTc * (Ci.x * Fi.y + Ci.y * Fi.w);
    float Fn10 = Fi.z + DTc * (Ci.z * Fi.x + Ci.w * Fi.z);
    float Fn11 = Fi.w + DTc * (Ci.z * Fi.y + Ci.w * Fi.w);

    float px = xi.x * INV_DX, py = xi.y * INV_DX;
    int   bx = (int)floorf(px - 0.5f);
    int   by = (int)floorf(py - 0.5f);
    float fx = px - (float)bx;
    float fy = py - (float)by;
    float wxs[3] = {0.5f * (1.5f - fx) * (1.5f - fx),
                    0.75f - (fx - 1.0f) * (fx - 1.0f),
                    0.5f * (fx - 0.5f) * (fx - 0.5f)};
    float wys[3] = {0.5f * (1.5f - fy) * (1.5f - fy),
                    0.75f - (fy - 1.0f) * (fy - 1.0f),
                    0.5f * (fy - 0.5f) * (fy - 0.5f)};

    float accvx = 0.0f, accvy = 0.0f;
    float accC00 = 0.0f, accC01 = 0.0f, accC10 = 0.0f, accC11 = 0.0f;

#pragma unroll
    for (int ii = 0; ii < 3; ii++) {
        float gxx = (float)(bx + ii) * DXc;
#pragma unroll
        for (int jj = 0; jj < 3; jj++) {
            float wt = wxs[ii] * wys[jj];
            float2 gvn = gv[(bx + ii) * NGc + (by + jj)];
            float gxy = (float)(by + jj) * DXc;
            accvx  += wt * gvn.x;
            accvy  += wt * gvn.y;
            accC00 += wt * gvn.x * gxx;
            accC01 += wt * gvn.x * gxy;
            accC10 += wt * gvn.y * gxx;
            accC11 += wt * gvn.y * gxy;
        }
    }

    const float k4 = 4.0f * INV_DX * INV_DX;
    out_x[i]   = make_float2(xi.x + DTc * vi.x, xi.y + DTc * vi.y);
    out_v[i]   = make_float2(accvx, accvy);
    out_C[i]   = make_float4(k4 * (accC00 - accvx * xi.x),
                             k4 * (accC01 - accvx * xi.y),
                             k4 * (accC10 - accvy * xi.x),
                             k4 * (accC11 - accvy * xi.y));
    out_F[i]   = make_float4(Fn00, Fn01, Fn10, Fn11);
    out_mat[i] = (float)material[i];
    out_Jp[i]  = Jp[i];
}

// ---------------------------------------------------------------------------
extern "C" void kernel_launch(void* const* d_in, const int* in_sizes, int n_in,
                              void* d_out, int out_size, void* d_ws, size_t ws_size,
                              hipStream_t stream)
{
    const float2* x  = (const float2*)d_in[0];
    const float2* v  = (const float2*)d_in[1];
    const float4* C  = (const float4*)d_in[2];
    const float4* F  = (const float4*)d_in[3];
    const int* material = (const int*)d_in[4];
    const float* Jp  = (const float*)d_in[5];
    const float* W1  = (const float*)d_in[8];
    const float* b1  = (const float*)d_in[9];
    const float* W2  = (const float*)d_in[10];
    const float* b2  = (const float*)d_in[11];
    const float* W3  = (const float*)d_in[12];
    const float* b3  = (const float*)d_in[13];
    const float* W4  = (const float*)d_in[14];

    const int n = in_sizes[0] / 2;

    // d_ws: grid (3*NCELL) + gcnt (NBIN) + binoff (NBIN) + gv (NCELL float2)
    float*    grid   = (float*)d_ws;
    unsigned* gcnt   = (unsigned*)(grid + 3 * NCELL);
    unsigned* binoff = gcnt + NBIN;
    float2*   gv     = (float2*)(binoff + NBIN);

    float* out = (float*)d_out;
    float2* out_x   = (float2*)out;                    // 0..2N
    float2* out_v   = (float2*)(out + 2 * (size_t)n);  // 2N..4N
    float4* out_C   = (float4*)(out + 4 * (size_t)n);  // 4N..8N
    float4* out_F   = (float4*)(out + 8 * (size_t)n);  // 8N..12N
    float*  out_mat = out + 12 * (size_t)n;            // 12N..13N
    float*  out_Jp  = out + 13 * (size_t)n;            // 13N..14N

    // middle-phase scratch inside d_out (consumed before g2p overwrites):
    float4*   recs = (float4*)(out + 2 * (size_t)n);   // 8N floats: 2N..10N
    unsigned* key  = (unsigned*)out_mat;               // N u32:     12N..13N

    hipMemsetAsync(d_ws, 0, (3 * NCELL + NBIN) * sizeof(float), stream);

    int s1_blocks = (n + S1_BLK * S1_PPT - 1) / (S1_BLK * S1_PPT);
    int blocks    = (n + 255) / 256;
    bin_kernel<<<s1_blocks, S1_BLK, 0, stream>>>(x, key, gcnt, n);
    scan_kernel<<<1, NBIN, 0, stream>>>(gcnt, binoff);
    stagea_kernel<<<blocks, 256, 0, stream>>>(x, v, C, F, W1, b1, W2, b2, W3, b3, W4,
                                              key, binoff, recs, n);
    p2g_kernel<<<NBIN * MAXCH, 256, 0, stream>>>(recs, gcnt, binoff, grid);
    grid_kernel<<<(NCELL + 255) / 256, 256, 0, stream>>>(grid, gv);
    g2p_kernel<<<blocks, 256, 0, stream>>>(x, v, C, F, material, Jp, gv,
                                           out_x, out_v, out_C, out_F, out_mat, out_Jp, n);
}

// Round 6
// 297.101 us; speedup vs baseline: 12.8022x; 1.5243x over previous
//
#include <hip/hip_runtime.h>
#include <math.h>

constexpr int   NGc    = 128;
constexpr int   NCELL  = NGc * NGc;
constexpr int   NBIN   = 128 * 32;          // bin = (bx, by>>2) : 4096
constexpr float DTc    = 1e-4f;
constexpr float DXc    = 1.0f / 128.0f;
constexpr float INV_DX = 128.0f;
constexpr float P_VOLc = (DXc * 0.5f) * (DXc * 0.5f);
constexpr float P_MASSc = P_VOLc * 1.0f;
constexpr float GRAV   = 9.8f;
constexpr float STRESS_COEF = -DTc * P_VOLc * 4.0f * INV_DX * INV_DX;

// ---------------------------------------------------------------------------
// S1: bin to 4096 bins (cell-row x col-group). LDS hist + local rank ->
// key = bin<<20 | pos_in_bin. 62 blocks so global merge is only ~250K atomics.
// ---------------------------------------------------------------------------
constexpr int S1_PPT = 16;
constexpr int S1_BLK = 1024;

__global__ __launch_bounds__(1024) void bin_kernel(
    const float2* __restrict__ x, unsigned* __restrict__ key,
    unsigned* __restrict__ gcnt, int n)
{
    __shared__ unsigned hist[NBIN];
#pragma unroll
    for (int j = 0; j < NBIN / S1_BLK; j++)
        hist[threadIdx.x + j * S1_BLK] = 0;
    __syncthreads();

    int base_i = blockIdx.x * (S1_BLK * S1_PPT);
    unsigned t_arr[S1_PPT], r_arr[S1_PPT];
#pragma unroll
    for (int k = 0; k < S1_PPT; k++) {
        int i = base_i + k * S1_BLK + threadIdx.x;
        unsigned t = 0, r = 0;
        if (i < n) {
            float2 xi = x[i];
            int bx = (int)floorf(xi.x * INV_DX - 0.5f);
            int by = (int)floorf(xi.y * INV_DX - 0.5f);
            t = (unsigned)(bx * 32 + (by >> 2));
            r = atomicAdd(&hist[t], 1u);
        }
        t_arr[k] = t; r_arr[k] = r;
    }
    __syncthreads();

#pragma unroll
    for (int j = 0; j < NBIN / S1_BLK; j++) {
        int b = threadIdx.x + j * S1_BLK;
        unsigned c = hist[b];
        __syncthreads();
        hist[b] = c ? atomicAdd(&gcnt[b], c) : 0u;
        __syncthreads();
    }

#pragma unroll
    for (int k = 0; k < S1_PPT; k++) {
        int i = base_i + k * S1_BLK + threadIdx.x;
        if (i < n)
            key[i] = (t_arr[k] << 20) | (hist[t_arr[k]] + r_arr[k]);
    }
}

// ---------------------------------------------------------------------------
// S2: exclusive scan over 4096 bin counts (single block, 4/thread) + sentinel
// ---------------------------------------------------------------------------
__global__ __launch_bounds__(1024) void scan_kernel(
    const unsigned* __restrict__ gcnt, unsigned* __restrict__ binoff)
{
    __shared__ unsigned s[1024];
    int t = threadIdx.x;
    unsigned v0 = gcnt[4 * t], v1 = gcnt[4 * t + 1];
    unsigned v2 = gcnt[4 * t + 2], v3 = gcnt[4 * t + 3];
    unsigned p = v0 + v1 + v2 + v3;
    s[t] = p;
    __syncthreads();
    for (int d = 1; d < 1024; d <<= 1) {
        unsigned add = (t >= d) ? s[t - d] : 0u;
        __syncthreads();
        s[t] += add;
        __syncthreads();
    }
    unsigned base = s[t] - p;
    binoff[4 * t]     = base;
    binoff[4 * t + 1] = base + v0;
    binoff[4 * t + 2] = base + v0 + v1;
    binoff[4 * t + 3] = base + v0 + v1 + v2;
    if (t == 1023) binoff[4096] = s[1023];
}

// ---------------------------------------------------------------------------
// Stage A: coalesced per-particle NN stress; scatter packed 32B record
//   rec = {x, y, a00, a01, a10, a11, pvx, pvy} to bin-sorted slot.
// ---------------------------------------------------------------------------
__global__ __launch_bounds__(256) void stagea_kernel(
    const float2* __restrict__ x, const float2* __restrict__ v,
    const float4* __restrict__ C, const float4* __restrict__ F,
    const float* __restrict__ W1, const float* __restrict__ b1,
    const float* __restrict__ W2, const float* __restrict__ b2,
    const float* __restrict__ W3, const float* __restrict__ b3,
    const float* __restrict__ W4,
    const unsigned* __restrict__ key, const unsigned* __restrict__ binoff,
    float4* __restrict__ recs, int n)
{
    int i = blockIdx.x * 256 + threadIdx.x;
    if (i >= n) return;

    float2 xi = x[i];
    float2 vi = v[i];
    float4 Ci = C[i];
    float4 Fi = F[i];

    float Fn00 = Fi.x + DTc * (Ci.x * Fi.x + Ci.y * Fi.z);
    float Fn01 = Fi.y + DTc * (Ci.x * Fi.y + Ci.y * Fi.w);
    float Fn10 = Fi.z + DTc * (Ci.z * Fi.x + Ci.w * Fi.z);
    float Fn11 = Fi.w + DTc * (Ci.z * Fi.y + Ci.w * Fi.w);

    float Cm00 = Fn00 * Fn00 + Fn10 * Fn10;
    float Cm01 = Fn00 * Fn01 + Fn10 * Fn11;
    float Cm11 = Fn01 * Fn01 + Fn11 * Fn11;

    float tr  = Cm00 + Cm11;
    float det = Cm00 * Cm11 - Cm01 * Cm01;
    float g   = tr * tr - 4.0f * det;
    float gate = (g > 1e-8f) ? 1.0f : 0.0f;
    float delta = sqrtf(fmaxf(g, 1e-8f));
    float feat0 = 0.5f * (tr + delta);
    float feat1 = 0.5f * (tr - delta);

    float h1[16], h2[16], h3[16];
#pragma unroll
    for (int j = 0; j < 16; j++)
        h1[j] = fmaxf(W1[2 * j] * feat0 + W1[2 * j + 1] * feat1 + b1[j], 0.0f);
#pragma unroll
    for (int j = 0; j < 16; j++) {
        float a = b2[j];
#pragma unroll
        for (int kk = 0; kk < 16; kk++) a += W2[j * 16 + kk] * h1[kk];
        h2[j] = fmaxf(a, 0.0f);
    }
#pragma unroll
    for (int j = 0; j < 16; j++) {
        float a = b3[j];
#pragma unroll
        for (int kk = 0; kk < 16; kk++) a += W3[j * 16 + kk] * h2[kk];
        h3[j] = fmaxf(a, 0.0f);
    }

    float dh3[16];
#pragma unroll
    for (int j = 0; j < 16; j++) dh3[j] = (h3[j] > 0.0f) ? W4[j] : 0.0f;

    float dh2[16];
#pragma unroll
    for (int kk = 0; kk < 16; kk++) {
        float a = 0.0f;
#pragma unroll
        for (int j = 0; j < 16; j++) a += W3[j * 16 + kk] * dh3[j];
        dh2[kk] = (h2[kk] > 0.0f) ? a : 0.0f;
    }

    float dfeat0 = 0.0f, dfeat1 = 0.0f;
#pragma unroll
    for (int kk = 0; kk < 16; kk++) {
        float a = 0.0f;
#pragma unroll
        for (int j = 0; j < 16; j++) a += W2[j * 16 + kk] * dh2[j];
        float dh1k = (h1[kk] > 0.0f) ? a : 0.0f;
        dfeat0 += W1[2 * kk] * dh1k;
        dfeat1 += W1[2 * kk + 1] * dh1k;
    }

    float half_sum  = 0.5f * (dfeat0 + dfeat1);
    float half_diff = 0.5f * (dfeat0 - dfeat1);
    float inv_delta = 1.0f / delta;
    float dtr  = half_sum + half_diff * tr * inv_delta * gate;
    float ddet = half_diff * (-2.0f) * inv_delta * gate;

    float S00 = 2.0f * (dtr + ddet * Cm11);
    float S11 = 2.0f * (dtr + ddet * Cm00);
    float S01 = -2.0f * ddet * Cm01;

    float dF00 = Fn00 * S00 + Fn01 * S01;
    float dF01 = Fn00 * S01 + Fn01 * S11;
    float dF10 = Fn10 * S00 + Fn11 * S01;
    float dF11 = Fn10 * S01 + Fn11 * S11;

    float a00 = STRESS_COEF * dF00 + P_MASSc * Ci.x;
    float a01 = STRESS_COEF * dF01 + P_MASSc * Ci.y;
    float a10 = STRESS_COEF * dF10 + P_MASSc * Ci.z;
    float a11 = STRESS_COEF * dF11 + P_MASSc * Ci.w;

    unsigned k = key[i];
    unsigned pos = binoff[k >> 20] + (k & 0xFFFFFu);

    recs[2 * (size_t)pos]     = make_float4(xi.x, xi.y, a00, a01);
    recs[2 * (size_t)pos + 1] = make_float4(a10, a11, P_MASSc * vi.x, P_MASSc * vi.y);
}

// ---------------------------------------------------------------------------
// Gather-form grid build: one wave per grid node. Streams the node's 3 row-
// segments of records, register-accumulates {momx,momy,mass}, butterfly-
// reduces, writes gv with mass-div + gravity + boundaries fused. No atomics.
// ---------------------------------------------------------------------------
__global__ __launch_bounds__(256) void grid_gather_kernel(
    const float4* __restrict__ recs, const unsigned* __restrict__ binoff,
    float2* __restrict__ gv)
{
    int wid  = threadIdx.x >> 6;
    int lane = threadIdx.x & 63;
    int node = blockIdx.x * 4 + wid;      // 4096 blocks * 4 waves = 16384 nodes
    int gi = node >> 7;
    int gj = node & 127;

    const float gxx = (float)gi * DXc;
    const float gxy = (float)gj * DXc;

    float accx = 0.0f, accy = 0.0f, accm = 0.0f;

    int c0 = max(gj - 2, 0) >> 2;
    int c1 = min(gj, 127) >> 2;

#pragma unroll
    for (int r = 0; r < 3; r++) {
        int bx = gi - 2 + r;              // particle base row; ii = gi-bx = 2-r
        if (bx < 0 || bx > 127) continue; // wave-uniform branch
        int lo = (int)binoff[bx * 32 + c0];
        int hi = (int)binoff[bx * 32 + c1 + 1];
        for (int k = lo + lane; k < hi; k += 64) {
            float4 r0 = recs[2 * (size_t)k];
            float4 r1 = recs[2 * (size_t)k + 1];

            float py = r0.y * INV_DX;
            int   by = (int)floorf(py - 0.5f);
            int   jj = gj - by;
            bool  ok = (jj >= 0) && (jj <= 2);

            float fy = py - (float)by;
            float fx = r0.x * INV_DX - (float)bx;

            float wx;
            if (r == 0)      wx = 0.5f * (fx - 0.5f) * (fx - 0.5f);   // ii = 2
            else if (r == 1) wx = 0.75f - (fx - 1.0f) * (fx - 1.0f);  // ii = 1
            else             wx = 0.5f * (1.5f - fx) * (1.5f - fx);   // ii = 0

            float wy0 = 0.5f * (1.5f - fy) * (1.5f - fy);
            float wy1 = 0.75f - (fy - 1.0f) * (fy - 1.0f);
            float wy2 = 0.5f * (fy - 0.5f) * (fy - 0.5f);
            float wy = (jj == 0) ? wy0 : ((jj == 1) ? wy1 : wy2);

            float wt = ok ? (wx * wy) : 0.0f;
            float dxp = gxx - r0.x;
            float dyp = gxy - r0.y;
            accx += wt * (r1.z + r0.z * dxp + r0.w * dyp);
            accy += wt * (r1.w + r1.x * dxp + r1.y * dyp);
            accm += wt * P_MASSc;
        }
    }

#pragma unroll
    for (int off = 32; off >= 1; off >>= 1) {
        accx += __shfl_xor(accx, off, 64);
        accy += __shfl_xor(accy, off, 64);
        accm += __shfl_xor(accm, off, 64);
    }

    if (lane == 0) {
        float vx = accx, vy = accy;
        if (accm > 0.0f) {
            float inv_m = 1.0f / accm;
            vx *= inv_m;
            vy *= inv_m;
        }
        vy -= DTc * GRAV;
        if (gi < 3)        vx = fmaxf(vx, 0.0f);
        if (gi >= NGc - 3) vx = fminf(vx, 0.0f);
        if (gj < 3)        vy = fmaxf(vy, 0.0f);
        if (gj >= NGc - 3) vy = fminf(vy, 0.0f);
        gv[node] = make_float2(vx, vy);
    }
}

// ---------------------------------------------------------------------------
// G2P (+ Fnew recompute and write, coalesced)
// ---------------------------------------------------------------------------
__global__ __launch_bounds__(256) void g2p_kernel(
    const float2* __restrict__ x, const float2* __restrict__ v,
    const float4* __restrict__ C, const float4* __restrict__ F,
    const int* __restrict__ material, const float* __restrict__ Jp,
    const float2* __restrict__ gv,
    float2* __restrict__ out_x, float2* __restrict__ out_v,
    float4* __restrict__ out_C, float4* __restrict__ out_F,
    float* __restrict__ out_mat, float* __restrict__ out_Jp, int n)
{
    int i = blockIdx.x * 256 + threadIdx.x;
    if (i >= n) return;

    float2 xi = x[i];
    float2 vi = v[i];
    float4 Ci = C[i];
    float4 Fi = F[i];

    float Fn00 = Fi.x + DTc * (Ci.x * Fi.x + Ci.y * Fi.z);
    float Fn01 = Fi.y + DTc * (Ci.x * Fi.y + Ci.y * Fi.w);
    float Fn10 = Fi.z + DTc * (Ci.z * Fi.x + Ci.w * Fi.z);
    float Fn11 = Fi.w + DTc * (Ci.z * Fi.y + Ci.w * Fi.w);

    float px = xi.x * INV_DX, py = xi.y * INV_DX;
    int   bx = (int)floorf(px - 0.5f);
    int   by = (int)floorf(py - 0.5f);
    float fx = px - (float)bx;
    float fy = py - (float)by;
    float wxs[3] = {0.5f * (1.5f - fx) * (1.5f - fx),
                    0.75f - (fx - 1.0f) * (fx - 1.0f),
                    0.5f * (fx - 0.5f) * (fx - 0.5f)};
    float wys[3] = {0.5f * (1.5f - fy) * (1.5f - fy),
                    0.75f - (fy - 1.0f) * (fy - 1.0f),
                    0.5f * (fy - 0.5f) * (fy - 0.5f)};

    float accvx = 0.0f, accvy = 0.0f;
    float accC00 = 0.0f, accC01 = 0.0f, accC10 = 0.0f, accC11 = 0.0f;

#pragma unroll
    for (int ii = 0; ii < 3; ii++) {
        float gxx = (float)(bx + ii) * DXc;
#pragma unroll
        for (int jj = 0; jj < 3; jj++) {
            float wt = wxs[ii] * wys[jj];
            float2 gvn = gv[(bx + ii) * NGc + (by + jj)];
            float gxy = (float)(by + jj) * DXc;
            accvx  += wt * gvn.x;
            accvy  += wt * gvn.y;
            accC00 += wt * gvn.x * gxx;
            accC01 += wt * gvn.x * gxy;
            accC10 += wt * gvn.y * gxx;
            accC11 += wt * gvn.y * gxy;
        }
    }

    const float k4 = 4.0f * INV_DX * INV_DX;
    out_x[i]   = make_float2(xi.x + DTc * vi.x, xi.y + DTc * vi.y);
    out_v[i]   = make_float2(accvx, accvy);
    out_C[i]   = make_float4(k4 * (accC00 - accvx * xi.x),
                             k4 * (accC01 - accvx * xi.y),
                             k4 * (accC10 - accvy * xi.x),
                             k4 * (accC11 - accvy * xi.y));
    out_F[i]   = make_float4(Fn00, Fn01, Fn10, Fn11);
    out_mat[i] = (float)material[i];
    out_Jp[i]  = Jp[i];
}

// ---------------------------------------------------------------------------
extern "C" void kernel_launch(void* const* d_in, const int* in_sizes, int n_in,
                              void* d_out, int out_size, void* d_ws, size_t ws_size,
                              hipStream_t stream)
{
    const float2* x  = (const float2*)d_in[0];
    const float2* v  = (const float2*)d_in[1];
    const float4* C  = (const float4*)d_in[2];
    const float4* F  = (const float4*)d_in[3];
    const int* material = (const int*)d_in[4];
    const float* Jp  = (const float*)d_in[5];
    const float* W1  = (const float*)d_in[8];
    const float* b1  = (const float*)d_in[9];
    const float* W2  = (const float*)d_in[10];
    const float* b2  = (const float*)d_in[11];
    const float* W3  = (const float*)d_in[12];
    const float* b3  = (const float*)d_in[13];
    const float* W4  = (const float*)d_in[14];

    const int n = in_sizes[0] / 2;

    // d_ws: gcnt (NBIN u32) + binoff (NBIN+1 u32) + gv (NCELL float2)
    unsigned* gcnt   = (unsigned*)d_ws;
    unsigned* binoff = gcnt + NBIN;
    float2*   gv     = (float2*)(binoff + NBIN + 1);

    float* out = (float*)d_out;
    float2* out_x   = (float2*)out;                    // 0..2N
    float2* out_v   = (float2*)(out + 2 * (size_t)n);  // 2N..4N
    float4* out_C   = (float4*)(out + 4 * (size_t)n);  // 4N..8N
    float4* out_F   = (float4*)(out + 8 * (size_t)n);  // 8N..12N
    float*  out_mat = out + 12 * (size_t)n;            // 12N..13N
    float*  out_Jp  = out + 13 * (size_t)n;            // 13N..14N

    // middle-phase scratch inside d_out (consumed before g2p overwrites):
    float4*   recs = (float4*)(out + 2 * (size_t)n);   // 8N floats: 2N..10N
    unsigned* key  = (unsigned*)out_mat;               // N u32:     12N..13N

    hipMemsetAsync(gcnt, 0, NBIN * sizeof(unsigned), stream);

    int s1_blocks = (n + S1_BLK * S1_PPT - 1) / (S1_BLK * S1_PPT);
    int blocks    = (n + 255) / 256;
    bin_kernel<<<s1_blocks, S1_BLK, 0, stream>>>(x, key, gcnt, n);
    scan_kernel<<<1, 1024, 0, stream>>>(gcnt, binoff);
    stagea_kernel<<<blocks, 256, 0, stream>>>(x, v, C, F, W1, b1, W2, b2, W3, b3, W4,
                                              key, binoff, recs, n);
    grid_gather_kernel<<<NCELL / 4, 256, 0, stream>>>(recs, binoff, gv);
    g2p_kernel<<<blocks, 256, 0, stream>>>(x, v, C, F, material, Jp, gv,
                                           out_x, out_v, out_C, out_F, out_mat, out_Jp, n);
}

// Round 7
// 280.006 us; speedup vs baseline: 13.5837x; 1.0611x over previous
//
#include <hip/hip_runtime.h>
#include <math.h>

constexpr int   NGc    = 128;
constexpr int   NCELL  = NGc * NGc;
constexpr int   NBIN   = 128 * 32;          // bin = (bx, by>>2) : 4096
constexpr float DTc    = 1e-4f;
constexpr float DXc    = 1.0f / 128.0f;
constexpr float INV_DX = 128.0f;
constexpr float P_VOLc = (DXc * 0.5f) * (DXc * 0.5f);
constexpr float P_MASSc = P_VOLc * 1.0f;
constexpr float GRAV   = 9.8f;
constexpr float STRESS_COEF = -DTc * P_VOLc * 4.0f * INV_DX * INV_DX;

// ---------------------------------------------------------------------------
// S1: bin to 4096 bins (cell-row x col-group). LDS hist + local rank ->
// key = bin<<20 | pos_in_bin.
// ---------------------------------------------------------------------------
constexpr int S1_PPT = 16;
constexpr int S1_BLK = 1024;

__global__ __launch_bounds__(1024) void bin_kernel(
    const float2* __restrict__ x, unsigned* __restrict__ key,
    unsigned* __restrict__ gcnt, int n)
{
    __shared__ unsigned hist[NBIN];
#pragma unroll
    for (int j = 0; j < NBIN / S1_BLK; j++)
        hist[threadIdx.x + j * S1_BLK] = 0;
    __syncthreads();

    int base_i = blockIdx.x * (S1_BLK * S1_PPT);
    unsigned t_arr[S1_PPT], r_arr[S1_PPT];
#pragma unroll
    for (int k = 0; k < S1_PPT; k++) {
        int i = base_i + k * S1_BLK + threadIdx.x;
        unsigned t = 0, r = 0;
        if (i < n) {
            float2 xi = x[i];
            int bx = (int)floorf(xi.x * INV_DX - 0.5f);
            int by = (int)floorf(xi.y * INV_DX - 0.5f);
            t = (unsigned)(bx * 32 + (by >> 2));
            r = atomicAdd(&hist[t], 1u);
        }
        t_arr[k] = t; r_arr[k] = r;
    }
    __syncthreads();

#pragma unroll
    for (int j = 0; j < NBIN / S1_BLK; j++) {
        int b = threadIdx.x + j * S1_BLK;
        unsigned c = hist[b];
        __syncthreads();
        hist[b] = c ? atomicAdd(&gcnt[b], c) : 0u;
        __syncthreads();
    }

#pragma unroll
    for (int k = 0; k < S1_PPT; k++) {
        int i = base_i + k * S1_BLK + threadIdx.x;
        if (i < n)
            key[i] = (t_arr[k] << 20) | (hist[t_arr[k]] + r_arr[k]);
    }
}

// ---------------------------------------------------------------------------
// S2: exclusive scan over 4096 bin counts (single block, 4/thread) + sentinel
// ---------------------------------------------------------------------------
__global__ __launch_bounds__(1024) void scan_kernel(
    const unsigned* __restrict__ gcnt, unsigned* __restrict__ binoff)
{
    __shared__ unsigned s[1024];
    int t = threadIdx.x;
    unsigned v0 = gcnt[4 * t], v1 = gcnt[4 * t + 1];
    unsigned v2 = gcnt[4 * t + 2], v3 = gcnt[4 * t + 3];
    unsigned p = v0 + v1 + v2 + v3;
    s[t] = p;
    __syncthreads();
    for (int d = 1; d < 1024; d <<= 1) {
        unsigned add = (t >= d) ? s[t - d] : 0u;
        __syncthreads();
        s[t] += add;
        __syncthreads();
    }
    unsigned base = s[t] - p;
    binoff[4 * t]     = base;
    binoff[4 * t + 1] = base + v0;
    binoff[4 * t + 2] = base + v0 + v1;
    binoff[4 * t + 3] = base + v0 + v1 + v2;
    if (t == 1023) binoff[4096] = s[1023];
}

// ---------------------------------------------------------------------------
// Stage A: NN stress with LDS-staged weights (incl. transposes so all four
// matmul passes read contiguous float4 rows -> broadcast ds_read_b128).
// Scatter packed 32B record {x,y,a00,a01,a10,a11,pvx,pvy} to bin-sorted slot.
// ---------------------------------------------------------------------------
__global__ __launch_bounds__(256) void stagea_kernel(
    const float2* __restrict__ x, const float2* __restrict__ v,
    const float4* __restrict__ C, const float4* __restrict__ F,
    const float* __restrict__ W1, const float* __restrict__ b1,
    const float* __restrict__ W2, const float* __restrict__ b2,
    const float* __restrict__ W3, const float* __restrict__ b3,
    const float* __restrict__ W4,
    const unsigned* __restrict__ key, const unsigned* __restrict__ binoff,
    float4* __restrict__ recs, int n)
{
    __shared__ float sW1[32];
    __shared__ float sW2[256], sW2T[256];
    __shared__ float sW3[256], sW3T[256];
    __shared__ float sb1[16], sb2[16], sb3[16], sW4[16];

    {
        int t = threadIdx.x;
        float w2 = W2[t], w3 = W3[t];
        sW2[t] = w2;  sW2T[(t & 15) * 16 + (t >> 4)] = w2;
        sW3[t] = w3;  sW3T[(t & 15) * 16 + (t >> 4)] = w3;
        if (t < 32) sW1[t] = W1[t];
        if (t < 16) { sb1[t] = b1[t]; sb2[t] = b2[t]; sb3[t] = b3[t]; sW4[t] = W4[t]; }
    }
    __syncthreads();

    const float4* W2r  = (const float4*)sW2;    // row j = W2r[4j .. 4j+3]
    const float4* W2Tr = (const float4*)sW2T;
    const float4* W3r  = (const float4*)sW3;
    const float4* W3Tr = (const float4*)sW3T;

    int i = blockIdx.x * 256 + threadIdx.x;
    if (i >= n) return;

    float2 xi = x[i];
    float2 vi = v[i];
    float4 Ci = C[i];
    float4 Fi = F[i];

    float Fn00 = Fi.x + DTc * (Ci.x * Fi.x + Ci.y * Fi.z);
    float Fn01 = Fi.y + DTc * (Ci.x * Fi.y + Ci.y * Fi.w);
    float Fn10 = Fi.z + DTc * (Ci.z * Fi.x + Ci.w * Fi.z);
    float Fn11 = Fi.w + DTc * (Ci.z * Fi.y + Ci.w * Fi.w);

    float Cm00 = Fn00 * Fn00 + Fn10 * Fn10;
    float Cm01 = Fn00 * Fn01 + Fn10 * Fn11;
    float Cm11 = Fn01 * Fn01 + Fn11 * Fn11;

    float tr  = Cm00 + Cm11;
    float det = Cm00 * Cm11 - Cm01 * Cm01;
    float g   = tr * tr - 4.0f * det;
    float gate = (g > 1e-8f) ? 1.0f : 0.0f;
    float delta = sqrtf(fmaxf(g, 1e-8f));
    float feat0 = 0.5f * (tr + delta);
    float feat1 = 0.5f * (tr - delta);

    float h1[16], h2[16], h3[16];
#pragma unroll
    for (int j = 0; j < 16; j++)
        h1[j] = fmaxf(sW1[2 * j] * feat0 + sW1[2 * j + 1] * feat1 + sb1[j], 0.0f);

#pragma unroll
    for (int j = 0; j < 16; j++) {
        float4 w0 = W2r[4 * j], w1 = W2r[4 * j + 1], w2 = W2r[4 * j + 2], w3 = W2r[4 * j + 3];
        float a = sb2[j]
            + w0.x * h1[0]  + w0.y * h1[1]  + w0.z * h1[2]  + w0.w * h1[3]
            + w1.x * h1[4]  + w1.y * h1[5]  + w1.z * h1[6]  + w1.w * h1[7]
            + w2.x * h1[8]  + w2.y * h1[9]  + w2.z * h1[10] + w2.w * h1[11]
            + w3.x * h1[12] + w3.y * h1[13] + w3.z * h1[14] + w3.w * h1[15];
        h2[j] = fmaxf(a, 0.0f);
    }
#pragma unroll
    for (int j = 0; j < 16; j++) {
        float4 w0 = W3r[4 * j], w1 = W3r[4 * j + 1], w2 = W3r[4 * j + 2], w3 = W3r[4 * j + 3];
        float a = sb3[j]
            + w0.x * h2[0]  + w0.y * h2[1]  + w0.z * h2[2]  + w0.w * h2[3]
            + w1.x * h2[4]  + w1.y * h2[5]  + w1.z * h2[6]  + w1.w * h2[7]
            + w2.x * h2[8]  + w2.y * h2[9]  + w2.z * h2[10] + w2.w * h2[11]
            + w3.x * h2[12] + w3.y * h2[13] + w3.z * h2[14] + w3.w * h2[15];
        h3[j] = fmaxf(a, 0.0f);
    }

    // backward
    float dh3[16];
#pragma unroll
    for (int j = 0; j < 16; j++) dh3[j] = (h3[j] > 0.0f) ? sW4[j] : 0.0f;

    float dh2[16];
#pragma unroll
    for (int kk = 0; kk < 16; kk++) {
        float4 w0 = W3Tr[4 * kk], w1 = W3Tr[4 * kk + 1], w2 = W3Tr[4 * kk + 2], w3 = W3Tr[4 * kk + 3];
        float a =
              w0.x * dh3[0]  + w0.y * dh3[1]  + w0.z * dh3[2]  + w0.w * dh3[3]
            + w1.x * dh3[4]  + w1.y * dh3[5]  + w1.z * dh3[6]  + w1.w * dh3[7]
            + w2.x * dh3[8]  + w2.y * dh3[9]  + w2.z * dh3[10] + w2.w * dh3[11]
            + w3.x * dh3[12] + w3.y * dh3[13] + w3.z * dh3[14] + w3.w * dh3[15];
        dh2[kk] = (h2[kk] > 0.0f) ? a : 0.0f;
    }

    float dfeat0 = 0.0f, dfeat1 = 0.0f;
#pragma unroll
    for (int kk = 0; kk < 16; kk++) {
        float4 w0 = W2Tr[4 * kk], w1 = W2Tr[4 * kk + 1], w2 = W2Tr[4 * kk + 2], w3 = W2Tr[4 * kk + 3];
        float a =
              w0.x * dh2[0]  + w0.y * dh2[1]  + w0.z * dh2[2]  + w0.w * dh2[3]
            + w1.x * dh2[4]  + w1.y * dh2[5]  + w1.z * dh2[6]  + w1.w * dh2[7]
            + w2.x * dh2[8]  + w2.y * dh2[9]  + w2.z * dh2[10] + w2.w * dh2[11]
            + w3.x * dh2[12] + w3.y * dh2[13] + w3.z * dh2[14] + w3.w * dh2[15];
        float dh1k = (h1[kk] > 0.0f) ? a : 0.0f;
        dfeat0 += sW1[2 * kk] * dh1k;
        dfeat1 += sW1[2 * kk + 1] * dh1k;
    }

    float half_sum  = 0.5f * (dfeat0 + dfeat1);
    float half_diff = 0.5f * (dfeat0 - dfeat1);
    float inv_delta = 1.0f / delta;
    float dtr  = half_sum + half_diff * tr * inv_delta * gate;
    float ddet = half_diff * (-2.0f) * inv_delta * gate;

    float S00 = 2.0f * (dtr + ddet * Cm11);
    float S11 = 2.0f * (dtr + ddet * Cm00);
    float S01 = -2.0f * ddet * Cm01;

    float dF00 = Fn00 * S00 + Fn01 * S01;
    float dF01 = Fn00 * S01 + Fn01 * S11;
    float dF10 = Fn10 * S00 + Fn11 * S01;
    float dF11 = Fn10 * S01 + Fn11 * S11;

    float a00 = STRESS_COEF * dF00 + P_MASSc * Ci.x;
    float a01 = STRESS_COEF * dF01 + P_MASSc * Ci.y;
    float a10 = STRESS_COEF * dF10 + P_MASSc * Ci.z;
    float a11 = STRESS_COEF * dF11 + P_MASSc * Ci.w;

    unsigned k = key[i];
    unsigned pos = binoff[k >> 20] + (k & 0xFFFFFu);

    recs[2 * (size_t)pos]     = make_float4(xi.x, xi.y, a00, a01);
    recs[2 * (size_t)pos + 1] = make_float4(a10, a11, P_MASSc * vi.x, P_MASSc * vi.y);
}

// ---------------------------------------------------------------------------
// Gather-form grid build: one wave per grid node, register accumulate,
// butterfly reduce, fused grid update. No atomics.
// ---------------------------------------------------------------------------
__global__ __launch_bounds__(256) void grid_gather_kernel(
    const float4* __restrict__ recs, const unsigned* __restrict__ binoff,
    float2* __restrict__ gv)
{
    int wid  = threadIdx.x >> 6;
    int lane = threadIdx.x & 63;
    int node = blockIdx.x * 4 + wid;
    int gi = node >> 7;
    int gj = node & 127;

    const float gxx = (float)gi * DXc;
    const float gxy = (float)gj * DXc;

    float accx = 0.0f, accy = 0.0f, accm = 0.0f;

    int c0 = max(gj - 2, 0) >> 2;
    int c1 = min(gj, 127) >> 2;

#pragma unroll
    for (int r = 0; r < 3; r++) {
        int bx = gi - 2 + r;
        if (bx < 0 || bx > 127) continue;
        int lo = (int)binoff[bx * 32 + c0];
        int hi = (int)binoff[bx * 32 + c1 + 1];
        for (int k = lo + lane; k < hi; k += 64) {
            float4 r0 = recs[2 * (size_t)k];
            float4 r1 = recs[2 * (size_t)k + 1];

            float py = r0.y * INV_DX;
            int   by = (int)floorf(py - 0.5f);
            int   jj = gj - by;
            bool  ok = (jj >= 0) && (jj <= 2);

            float fy = py - (float)by;
            float fx = r0.x * INV_DX - (float)bx;

            float wx;
            if (r == 0)      wx = 0.5f * (fx - 0.5f) * (fx - 0.5f);   // ii = 2
            else if (r == 1) wx = 0.75f - (fx - 1.0f) * (fx - 1.0f);  // ii = 1
            else             wx = 0.5f * (1.5f - fx) * (1.5f - fx);   // ii = 0

            float wy0 = 0.5f * (1.5f - fy) * (1.5f - fy);
            float wy1 = 0.75f - (fy - 1.0f) * (fy - 1.0f);
            float wy2 = 0.5f * (fy - 0.5f) * (fy - 0.5f);
            float wy = (jj == 0) ? wy0 : ((jj == 1) ? wy1 : wy2);

            float wt = ok ? (wx * wy) : 0.0f;
            float dxp = gxx - r0.x;
            float dyp = gxy - r0.y;
            accx += wt * (r1.z + r0.z * dxp + r0.w * dyp);
            accy += wt * (r1.w + r1.x * dxp + r1.y * dyp);
            accm += wt * P_MASSc;
        }
    }

#pragma unroll
    for (int off = 32; off >= 1; off >>= 1) {
        accx += __shfl_xor(accx, off, 64);
        accy += __shfl_xor(accy, off, 64);
        accm += __shfl_xor(accm, off, 64);
    }

    if (lane == 0) {
        float vx = accx, vy = accy;
        if (accm > 0.0f) {
            float inv_m = 1.0f / accm;
            vx *= inv_m;
            vy *= inv_m;
        }
        vy -= DTc * GRAV;
        if (gi < 3)        vx = fmaxf(vx, 0.0f);
        if (gi >= NGc - 3) vx = fminf(vx, 0.0f);
        if (gj < 3)        vy = fmaxf(vy, 0.0f);
        if (gj >= NGc - 3) vy = fminf(vy, 0.0f);
        gv[node] = make_float2(vx, vy);
    }
}

// ---------------------------------------------------------------------------
// G2P (+ Fnew recompute and write, coalesced)
// ---------------------------------------------------------------------------
__global__ __launch_bounds__(256) void g2p_kernel(
    const float2* __restrict__ x, const float2* __restrict__ v,
    const float4* __restrict__ C, const float4* __restrict__ F,
    const int* __restrict__ material, const float* __restrict__ Jp,
    const float2* __restrict__ gv,
    float2* __restrict__ out_x, float2* __restrict__ out_v,
    float4* __restrict__ out_C, float4* __restrict__ out_F,
    float* __restrict__ out_mat, float* __restrict__ out_Jp, int n)
{
    int i = blockIdx.x * 256 + threadIdx.x;
    if (i >= n) return;

    float2 xi = x[i];
    float2 vi = v[i];
    float4 Ci = C[i];
    float4 Fi = F[i];

    float Fn00 = Fi.x + DTc * (Ci.x * Fi.x + Ci.y * Fi.z);
    float Fn01 = Fi.y + DTc * (Ci.x * Fi.y + Ci.y * Fi.w);
    float Fn10 = Fi.z + DTc * (Ci.z * Fi.x + Ci.w * Fi.z);
    float Fn11 = Fi.w + DTc * (Ci.z * Fi.y + Ci.w * Fi.w);

    float px = xi.x * INV_DX, py = xi.y * INV_DX;
    int   bx = (int)floorf(px - 0.5f);
    int   by = (int)floorf(py - 0.5f);
    float fx = px - (float)bx;
    float fy = py - (float)by;
    float wxs[3] = {0.5f * (1.5f - fx) * (1.5f - fx),
                    0.75f - (fx - 1.0f) * (fx - 1.0f),
                    0.5f * (fx - 0.5f) * (fx - 0.5f)};
    float wys[3] = {0.5f * (1.5f - fy) * (1.5f - fy),
                    0.75f - (fy - 1.0f) * (fy - 1.0f),
                    0.5f * (fy - 0.5f) * (fy - 0.5f)};

    float accvx = 0.0f, accvy = 0.0f;
    float accC00 = 0.0f, accC01 = 0.0f, accC10 = 0.0f, accC11 = 0.0f;

#pragma unroll
    for (int ii = 0; ii < 3; ii++) {
        float gxx = (float)(bx + ii) * DXc;
#pragma unroll
        for (int jj = 0; jj < 3; jj++) {
            float wt = wxs[ii] * wys[jj];
            float2 gvn = gv[(bx + ii) * NGc + (by + jj)];
            float gxy = (float)(by + jj) * DXc;
            accvx  += wt * gvn.x;
            accvy  += wt * gvn.y;
            accC00 += wt * gvn.x * gxx;
            accC01 += wt * gvn.x * gxy;
            accC10 += wt * gvn.y * gxx;
            accC11 += wt * gvn.y * gxy;
        }
    }

    const float k4 = 4.0f * INV_DX * INV_DX;
    out_x[i]   = make_float2(xi.x + DTc * vi.x, xi.y + DTc * vi.y);
    out_v[i]   = make_float2(accvx, accvy);
    out_C[i]   = make_float4(k4 * (accC00 - accvx * xi.x),
                             k4 * (accC01 - accvx * xi.y),
                             k4 * (accC10 - accvy * xi.x),
                             k4 * (accC11 - accvy * xi.y));
    out_F[i]   = make_float4(Fn00, Fn01, Fn10, Fn11);
    out_mat[i] = (float)material[i];
    out_Jp[i]  = Jp[i];
}

// ---------------------------------------------------------------------------
extern "C" void kernel_launch(void* const* d_in, const int* in_sizes, int n_in,
                              void* d_out, int out_size, void* d_ws, size_t ws_size,
                              hipStream_t stream)
{
    const float2* x  = (const float2*)d_in[0];
    const float2* v  = (const float2*)d_in[1];
    const float4* C  = (const float4*)d_in[2];
    const float4* F  = (const float4*)d_in[3];
    const int* material = (const int*)d_in[4];
    const float* Jp  = (const float*)d_in[5];
    const float* W1  = (const float*)d_in[8];
    const float* b1  = (const float*)d_in[9];
    const float* W2  = (const float*)d_in[10];
    const float* b2  = (const float*)d_in[11];
    const float* W3  = (const float*)d_in[12];
    const float* b3  = (const float*)d_in[13];
    const float* W4  = (const float*)d_in[14];

    const int n = in_sizes[0] / 2;

    // d_ws: gcnt (NBIN u32) + binoff (NBIN+1 u32) + gv (NCELL float2)
    unsigned* gcnt   = (unsigned*)d_ws;
    unsigned* binoff = gcnt + NBIN;
    float2*   gv     = (float2*)(binoff + NBIN + 1);

    float* out = (float*)d_out;
    float2* out_x   = (float2*)out;                    // 0..2N
    float2* out_v   = (float2*)(out + 2 * (size_t)n);  // 2N..4N
    float4* out_C   = (float4*)(out + 4 * (size_t)n);  // 4N..8N
    float4* out_F   = (float4*)(out + 8 * (size_t)n);  // 8N..12N
    float*  out_mat = out + 12 * (size_t)n;            // 12N..13N
    float*  out_Jp  = out + 13 * (size_t)n;            // 13N..14N

    // middle-phase scratch inside d_out (consumed before g2p overwrites):
    float4*   recs = (float4*)(out + 2 * (size_t)n);   // 8N floats: 2N..10N
    unsigned* key  = (unsigned*)out_mat;               // N u32:     12N..13N

    hipMemsetAsync(gcnt, 0, NBIN * sizeof(unsigned), stream);

    int s1_blocks = (n + S1_BLK * S1_PPT - 1) / (S1_BLK * S1_PPT);
    int blocks    = (n + 255) / 256;
    bin_kernel<<<s1_blocks, S1_BLK, 0, stream>>>(x, key, gcnt, n);
    scan_kernel<<<1, 1024, 0, stream>>>(gcnt, binoff);
    stagea_kernel<<<blocks, 256, 0, stream>>>(x, v, C, F, W1, b1, W2, b2, W3, b3, W4,
                                              key, binoff, recs, n);
    grid_gather_kernel<<<NCELL / 4, 256, 0, stream>>>(recs, binoff, gv);
    g2p_kernel<<<blocks, 256, 0, stream>>>(x, v, C, F, material, Jp, gv,
                                           out_x, out_v, out_C, out_F, out_mat, out_Jp, n);
}